// Round 9
// baseline (412.619 us; speedup 1.0000x reference)
//
#include <hip/hip_runtime.h>
#include <hip/hip_bf16.h>
#include <stdint.h>

typedef __attribute__((ext_vector_type(8))) short short8v;     // 8 x bf16 (MFMA A/B frag)
typedef __attribute__((ext_vector_type(4))) float float4v;     // MFMA C/D frag / vec loads
typedef __attribute__((ext_vector_type(4))) unsigned short ushort4v;
typedef __attribute__((ext_vector_type(4))) unsigned int uint4v;

#define FINF __builtin_huge_valf()
#define BB 64
#define NN 512
#define DD 256
#define TT_SKEW 640   // skew rows: tau = r + 2*(j>>3) in [0, 511+126] -> pad to 640

// ws layout (bytes):
//   [0,        16777216)  xnb bf16 [B][N][D]
//   [16777216, 33554432)  ynb bf16 [B][N][D]
//   [33554432, 75497472)  cost_skew bf16 [B][640][512]  (cell (r,j) at row tau=r+2*(j>>3), col j)
//   [75497472, 75501568)  negbuf f32 [64] (+pad)
//   [75501568, 79695872)  decg u32 [B][16384]  (decision words)

static __device__ __forceinline__ unsigned short f2bf(float f) {
  union { float f; uint32_t u; } a; a.f = f;
  uint32_t r = a.u + 0x7fffu + ((a.u >> 16) & 1u);   // RNE
  return (unsigned short)(r >> 16);
}
static __device__ __forceinline__ float bf2f(uint16_t v) {
  return __uint_as_float(((uint32_t)v) << 16);
}

// ---------------- Kernel 0: zero the skew-layout pad cells ----------------
__global__ __launch_bounds__(64) void pad_zero_kernel(uint16_t* __restrict__ skew)
{
  const int tau = blockIdx.x, b = blockIdx.y, g = threadIdx.x;
  const int r = tau - 2 * g;
  if (r < 0 || r > 511) {
    uint16_t* p = skew + ((size_t)b * TT_SKEW + tau) * NN + g * 8;
    *(uint4v*)p = (uint4v){0u, 0u, 0u, 0u};
  }
}

// ---------------- Kernel 1: row-normalize + cast to bf16 ----------------
__global__ __launch_bounds__(256) void norm_cast_kernel(
    const float* __restrict__ x, const float* __restrict__ y,
    uint16_t* __restrict__ xnb, uint16_t* __restrict__ ynb)
{
  const int wave = threadIdx.x >> 6, lane = threadIdx.x & 63;
  const int row = blockIdx.x * 4 + wave;
  const float* src; uint16_t* dst;
  if (row < BB * NN) { src = x + (size_t)row * DD;            dst = xnb + (size_t)row * DD; }
  else               { src = y + (size_t)(row - BB*NN) * DD;  dst = ynb + (size_t)(row - BB*NN) * DD; }
  const float4v v = *(const float4v*)(src + lane * 4);
  float s = v[0]*v[0] + v[1]*v[1] + v[2]*v[2] + v[3]*v[3];
  #pragma unroll
  for (int d = 1; d < 64; d <<= 1) s += __shfl_xor(s, d, 64);
  const float inv = 1.0f / fmaxf(sqrtf(s), 1e-8f);
  ushort4v o;
  o[0] = f2bf(v[0] * inv); o[1] = f2bf(v[1] * inv);
  o[2] = f2bf(v[2] * inv); o[3] = f2bf(v[3] * inv);
  *(ushort4v*)(dst + lane * 4) = o;
}

// ---------------- Kernel 2: cost = 1 - xn·yn -> bf16 skewed layout ----------------
__global__ __launch_bounds__(256) void gemm_cost_kernel(
    const uint16_t* __restrict__ xnb, const uint16_t* __restrict__ ynb,
    uint16_t* __restrict__ skew)
{
  __shared__ uint16_t As[128 * 32];
  __shared__ uint16_t Bs[128 * 32];
  const int bid = blockIdx.x;
  const int b = bid >> 4, tm = (bid >> 2) & 3, tn = bid & 3;
  const int tid = threadIdx.x, wave = tid >> 6, lane = tid & 63;
  const int wr = wave >> 1, wc = wave & 1;

  const char* Ab = (const char*)(xnb + (size_t)b * NN * DD + (size_t)tm * 128 * DD);
  const char* Bb = (const char*)(ynb + (size_t)b * NN * DD + (size_t)tn * 128 * DD);

  float4v acc[4][4];
  #pragma unroll
  for (int i = 0; i < 4; i++)
    #pragma unroll
    for (int j = 0; j < 4; j++) acc[i][j] = (float4v){0.f, 0.f, 0.f, 0.f};

  const int seg0 = wave * 2;
  const int o0 = seg0 * 1024 + lane * 16;
  const int o1 = o0 + 1024;
  const int r0 = o0 >> 6, c0 = o0 & 63;
  const int r1 = o1 >> 6, c1 = o1 & 63;

  for (int kk = 0; kk < 8; kk++) {
    const int kb = kk * 64;
    __builtin_amdgcn_global_load_lds(
        (const __attribute__((address_space(1))) uint32_t*)(Ab + (size_t)r0 * 512 + kb + c0),
        (__attribute__((address_space(3))) uint32_t*)((char*)As + seg0 * 1024), 16, 0, 0);
    __builtin_amdgcn_global_load_lds(
        (const __attribute__((address_space(1))) uint32_t*)(Ab + (size_t)r1 * 512 + kb + c1),
        (__attribute__((address_space(3))) uint32_t*)((char*)As + (seg0 + 1) * 1024), 16, 0, 0);
    __builtin_amdgcn_global_load_lds(
        (const __attribute__((address_space(1))) uint32_t*)(Bb + (size_t)r0 * 512 + kb + c0),
        (__attribute__((address_space(3))) uint32_t*)((char*)Bs + seg0 * 1024), 16, 0, 0);
    __builtin_amdgcn_global_load_lds(
        (const __attribute__((address_space(1))) uint32_t*)(Bb + (size_t)r1 * 512 + kb + c1),
        (__attribute__((address_space(3))) uint32_t*)((char*)Bs + (seg0 + 1) * 1024), 16, 0, 0);
    __syncthreads();

    short8v af[4], bfr[4];
    #pragma unroll
    for (int mi = 0; mi < 4; mi++) {
      const int rr = wr * 64 + mi * 16 + (lane & 15);
      af[mi] = *(const short8v*)((const char*)As + rr * 64 + (lane >> 4) * 16);
    }
    #pragma unroll
    for (int nj = 0; nj < 4; nj++) {
      const int rr = wc * 64 + nj * 16 + (lane & 15);
      bfr[nj] = *(const short8v*)((const char*)Bs + rr * 64 + (lane >> 4) * 16);
    }
    #pragma unroll
    for (int mi = 0; mi < 4; mi++)
      #pragma unroll
      for (int nj = 0; nj < 4; nj++)
        acc[mi][nj] = __builtin_amdgcn_mfma_f32_16x16x32_bf16(af[mi], bfr[nj], acc[mi][nj], 0, 0, 0);
    __syncthreads();
  }

  uint16_t* Cb = skew + (size_t)b * TT_SKEW * NN;
  #pragma unroll
  for (int mi = 0; mi < 4; mi++)
    #pragma unroll
    for (int nj = 0; nj < 4; nj++) {
      const int cc = tn * 128 + wc * 64 + nj * 16 + (lane & 15);
      const int lg = cc >> 3;
      #pragma unroll
      for (int v = 0; v < 4; v++) {
        const int rr = tm * 128 + wr * 64 + mi * 16 + (lane >> 4) * 4 + v;
        Cb[(size_t)(rr + 2 * lg) * NN + cc] = f2bf(1.0f - acc[mi][nj][v]);
      }
    }
}

// ---------------- Kernel 3: neg[b] = LSE over column sums ----------------
__global__ __launch_bounds__(256) void neg_lse_kernel(
    const uint16_t* __restrict__ skew, float* __restrict__ negbuf)
{
  __shared__ float sm[8];
  const int b = blockIdx.x, tid = threadIdx.x;
  const int wave = tid >> 6, lane = tid & 63;
  const uint32_t* p = (const uint32_t*)(skew + (size_t)b * TT_SKEW * NN) + tid;
  float s0 = 0.f, s1 = 0.f;
  #pragma unroll 8
  for (int t = 0; t < TT_SKEW; ++t) {
    const uint32_t w = p[t * 256];
    s0 += __uint_as_float(w << 16);
    s1 += __uint_as_float(w & 0xFFFF0000u);
  }
  float m = fmaxf(s0, s1);
  #pragma unroll
  for (int d = 1; d < 64; d <<= 1) m = fmaxf(m, __shfl_xor(m, d, 64));
  if (lane == 0) sm[wave] = m;
  __syncthreads();
  m = fmaxf(fmaxf(sm[0], sm[1]), fmaxf(sm[2], sm[3]));
  float e = expf(s0 - m) + expf(s1 - m);
  #pragma unroll
  for (int d = 1; d < 64; d <<= 1) e += __shfl_xor(e, d, 64);
  if (lane == 0) sm[4 + wave] = e;
  __syncthreads();
  if (tid == 0) negbuf[b] = m + logf(sm[4] + sm[5] + sm[6] + sm[7]);
}

// ---------------- Kernel 4: DTW forward, DUAL-BATCH per wave ----------------
// 32 blocks x 1 wave; block q processes batches 2q, 2q+1 simultaneously.
// Per batch: lane l owns cols [8l,8l+8); step t processes rows 2(t-l), +1.
// The two batches' dependency chains are independent -> their VALU work
// interleaves into each other's shfl/dep stalls (fwd was ~40% issue / ~60%
// stall at 1 batch/wave). 4-deep register ring per batch-row-pair (16 loads
// in flight), dataflow-tied s_waitcnt vmcnt(12).
// LDS: dec batch0 [0,64K) | dec batch1 [64K,128K) | dump 128K+
__global__ __launch_bounds__(64, 1) void dtw_fwd_kernel(
    const uint16_t* __restrict__ skew, uint32_t* __restrict__ decg)
{
  extern __shared__ char lds_raw[];
  const int l = threadIdx.x;
  const int q = blockIdx.x;
  const uint16_t* csk0 = skew + (size_t)(2 * q) * TT_SKEW * NN;
  const uint16_t* csk1 = skew + (size_t)(2 * q + 1) * TT_SKEW * NN;
  const uint64_t base0 = (uint64_t)(uintptr_t)csk0;
  const uint64_t base1 = (uint64_t)(uintptr_t)csk1;
  const bool is0 = (l == 0);
  const uint32_t voff_base = 16u * (uint32_t)l;
  const uint32_t dump_addr = 131072u + (((uint32_t)l) << 2);

  uint4v rA0[4], rA1[4], rB0[4], rB1[4];   // batch0 rows 2t/2t+1, batch1 rows
  #pragma unroll
  for (int i = 0; i < 4; ++i) {
    const uint32_t voA = voff_base + ((uint32_t)(2 * i) << 10);
    const uint32_t voB = voA + 1024u;
    asm volatile("global_load_dwordx4 %0, %1, %2" : "=v"(rA0[i]) : "v"(voA), "s"(base0));
    asm volatile("global_load_dwordx4 %0, %1, %2" : "=v"(rA1[i]) : "v"(voB), "s"(base0));
    asm volatile("global_load_dwordx4 %0, %1, %2" : "=v"(rB0[i]) : "v"(voA), "s"(base1));
    asm volatile("global_load_dwordx4 %0, %1, %2" : "=v"(rB1[i]) : "v"(voB), "s"(base1));
  }

  float tpA[8], tpB[8];
  #pragma unroll
  for (int c = 0; c < 8; ++c) { tpA[c] = FINF; tpB[c] = FINF; }
  float clA0 = FINF, clA1 = FINF, carA = FINF;
  float clB0 = FINF, clB1 = FINF, carB = FINF;

  auto STEP = [&](int t, uint32_t rlane, bool valid,
                  const uint4v A, const uint4v Bv,
                  float (&tp)[8], float &cl0, float &cl1, float &carry,
                  uint32_t dec_off) {
    float shA = __shfl_up(cl0, 1, 64);   // tc[r0][8l-1]
    float shB = __shfl_up(cl1, 1, 64);   // tc[r1][8l-1]
    if (is0) { shA = (t == 0) ? 0.0f : FINF; shB = FINF; }
    const float sh_p0 = carry;            // tc[r0-1][8l-1]
    carry = shB;

    float ca[8], cbv[8], S0[8], S1[8];
    #pragma unroll
    for (int k = 0; k < 4; ++k) {
      ca[2*k]    = __uint_as_float(A[k] << 16);
      ca[2*k+1]  = __uint_as_float(A[k] & 0xFFFF0000u);
      cbv[2*k]   = __uint_as_float(Bv[k] << 16);
      cbv[2*k+1] = __uint_as_float(Bv[k] & 0xFFFF0000u);
    }
    S0[0] = ca[0]; S1[0] = cbv[0];
    #pragma unroll
    for (int c = 1; c < 8; ++c) { S0[c] = S0[c-1] + ca[c]; S1[c] = S1[c-1] + cbv[c]; }

    // row 0
    float dcp0[8], mu0[8], w0[8], PW0[8], tn0[8];
    dcp0[0] = sh_p0;
    #pragma unroll
    for (int c = 1; c < 8; ++c) dcp0[c] = tp[c-1];
    #pragma unroll
    for (int c = 0; c < 8; ++c) mu0[c] = fminf(dcp0[c], tp[c]);
    w0[0] = mu0[0];
    #pragma unroll
    for (int c = 1; c < 8; ++c) w0[c] = mu0[c] - S0[c-1];
    PW0[0] = w0[0];
    #pragma unroll
    for (int c = 1; c < 8; ++c) PW0[c] = fminf(PW0[c-1], w0[c]);
    #pragma unroll
    for (int c = 0; c < 8; ++c) tn0[c] = fminf(PW0[c], shA) + S0[c];

    // row 1 (chains on row 0)
    float dcp1[8], mu1[8], w1[8], PW1[8], tn1[8];
    dcp1[0] = shA;
    #pragma unroll
    for (int c = 1; c < 8; ++c) dcp1[c] = tn0[c-1];
    #pragma unroll
    for (int c = 0; c < 8; ++c) mu1[c] = fminf(dcp1[c], tn0[c]);
    w1[0] = mu1[0];
    #pragma unroll
    for (int c = 1; c < 8; ++c) w1[c] = mu1[c] - S1[c-1];
    PW1[0] = w1[0];
    #pragma unroll
    for (int c = 1; c < 8; ++c) PW1[c] = fminf(PW1[c-1], w1[c]);
    #pragma unroll
    for (int c = 0; c < 8; ++c) tn1[c] = fminf(PW1[c], shB) + S1[c];

    // decisions (ref tie-break diag > up > left): dd=(lc<mu)?2:(up<dcp)
    uint32_t word = 0;
    {
      float lc0[8], lc1[8];
      lc0[0] = shA; lc1[0] = shB;
      #pragma unroll
      for (int c = 1; c < 8; ++c) { lc0[c] = tn0[c-1]; lc1[c] = tn1[c-1]; }
      #pragma unroll
      for (int c = 0; c < 8; ++c) {
        const uint32_t e0 = (tp[c] < dcp0[c]) ? 1u : 0u;
        const uint32_t d0 = (lc0[c] < mu0[c]) ? 2u : e0;
        const uint32_t e1 = (tn0[c] < dcp1[c]) ? 1u : 0u;
        const uint32_t d1 = (lc1[c] < mu1[c]) ? 2u : e1;
        word |= (d0 << (2 * c)) | (d1 << (16 + 2 * c));
      }
    }
    const uint32_t waddr = valid ? (dec_off + (rlane << 8) + (((uint32_t)l) << 2)) : dump_addr;
    *(uint32_t*)(lds_raw + waddr) = word;

    #pragma unroll
    for (int c = 0; c < 8; ++c) tp[c] = valid ? tn1[c] : tp[c];
    cl0 = valid ? tn0[7] : cl0;
    cl1 = tp[7];
  };

  for (int t0 = 0; t0 < 320; t0 += 4) {
    #pragma unroll
    for (int u = 0; u < 4; ++u) {
      const int t = t0 + u;
      asm volatile("s_waitcnt vmcnt(12)"
                   : "+v"(rA0[u]), "+v"(rA1[u]), "+v"(rB0[u]), "+v"(rB1[u]));
      const uint32_t rlane = (uint32_t)(t - l);
      const bool valid = rlane < 256u;
      STEP(t, rlane, valid, rA0[u], rA1[u], tpA, clA0, clA1, carA, 0u);
      STEP(t, rlane, valid, rB0[u], rB1[u], tpB, clB0, clB1, carB, 65536u);
      // refill rows 2(t+4), +1 (clamped; keeps exactly 16 loads in flight)
      int rr = 2 * (t + 4); if (rr > 638) rr = 638;
      const uint32_t voA = voff_base + ((uint32_t)rr << 10);
      const uint32_t voB = voA + 1024u;
      asm volatile("global_load_dwordx4 %0, %1, %2" : "=v"(rA0[u]) : "v"(voA), "s"(base0));
      asm volatile("global_load_dwordx4 %0, %1, %2" : "=v"(rA1[u]) : "v"(voB), "s"(base0));
      asm volatile("global_load_dwordx4 %0, %1, %2" : "=v"(rB0[u]) : "v"(voA), "s"(base1));
      asm volatile("global_load_dwordx4 %0, %1, %2" : "=v"(rB1[u]) : "v"(voB), "s"(base1));
    }
  }
  asm volatile("s_waitcnt vmcnt(0)" ::: "memory");

  // dump both batches' decisions (128KB) to global, coalesced
  uint32_t* dg = decg + (size_t)q * 32768;
  #pragma unroll 4
  for (int i = 0; i < 128; ++i)
    *(uint4v*)(dg + i * 256 + l * 4) = *(const uint4v*)(lds_raw + i * 1024 + l * 16);
}

// ---------------- Kernel 5: backtrack (region walk) + colpos + pos LSE ----------------
// 64 blocks. Per dependent round: load the TWO u32 words covering the 4x8
// region of (i,j) (independent LDS reads), then walk path steps inside the
// region in registers. ~5 path-steps per region -> ~200 dependent rounds.
__global__ __launch_bounds__(64, 1) void dtw_bt_kernel(
    const uint16_t* __restrict__ skew, const uint32_t* __restrict__ decg,
    const float* __restrict__ negbuf, float* __restrict__ out)
{
  extern __shared__ char lds_raw[];
  uint16_t* rlo    = (uint16_t*)(lds_raw + 65536);
  uint16_t* rhi    = (uint16_t*)(lds_raw + 66560);
  float*    colpos = (float*)  (lds_raw + 67584);
  const uint32_t* dec32 = (const uint32_t*)lds_raw;

  const int l = threadIdx.x;
  const int b = blockIdx.x;
  const uint16_t* csk = skew + (size_t)b * TT_SKEW * NN;
  const uint32_t* dg = decg + (size_t)b * 16384;

  #pragma unroll 4
  for (int i = 0; i < 64; ++i)
    *(uint4v*)(lds_raw + i * 1024 + l * 16) = *(const uint4v*)(dg + i * 256 + l * 4);
  for (int r = l; r < NN; r += 64) { rlo[r] = 1; rhi[r] = 0; colpos[r] = 0.0f; }
  __syncthreads();

  if (l == 0) {
    int i = NN - 1, j = NN - 1, hicur = NN - 1;
    while (i > 0 && j > 0) {
      const int a = i >> 2, g = j >> 3;
      const uint32_t w0 = dec32[a * 128 + g];        // rows 4a,4a+1
      const uint32_t w1 = dec32[a * 128 + 64 + g];   // rows 4a+2,4a+3
      while (i > 0 && j > 0 && (i >> 2) == a && (j >> 3) == g) {
        const uint32_t w = (i & 2) ? w1 : w0;
        const uint32_t dd = (w >> (((i & 1) << 4) + ((j & 7) << 1))) & 3u;
        if (dd == 2u) { j--; }           // left: stay in row
        else {
          rlo[i] = (uint16_t)j; rhi[i] = (uint16_t)hicur;  // leave row i
          i--;
          if (dd == 0u) j--;             // diag also moves left
          hicur = j;                     // entry column of new row
        }
      }
    }
    rlo[i] = (uint16_t)j; rhi[i] = (uint16_t)hicur;      // pending row at exit
  }
  __syncthreads();
  for (int r = l; r < NN; r += 64) {
    const int lo = rlo[r], hi = rhi[r];
    for (int j = lo; j <= hi; j++) {
      const float cv = bf2f(csk[(size_t)(r + 2 * (j >> 3)) * NN + j]);
      atomicAdd(&colpos[j], cv);
    }
  }
  if (l == 0 && rlo[0] != 0) atomicAdd(&colpos[0], bf2f(csk[0]));
  __syncthreads();

  float mv[8];
  float mx2 = -FINF;
  #pragma unroll
  for (int k = 0; k < 8; k++) { mv[k] = colpos[l + 64 * k]; mx2 = fmaxf(mx2, mv[k]); }
  #pragma unroll
  for (int d = 1; d < 64; d <<= 1) mx2 = fmaxf(mx2, __shfl_xor(mx2, d, 64));
  float se2 = 0.f;
  #pragma unroll
  for (int k = 0; k < 8; k++) se2 += expf(mv[k] - mx2);
  #pragma unroll
  for (int d = 1; d < 64; d <<= 1) se2 += __shfl_xor(se2, d, 64);
  const float pos = mx2 + logf(se2);

  if (l == 0) out[b] = pos - negbuf[b];
}

extern "C" void kernel_launch(void* const* d_in, const int* in_sizes, int n_in,
                              void* d_out, int out_size, void* d_ws, size_t ws_size,
                              hipStream_t stream)
{
  (void)in_sizes; (void)n_in; (void)out_size; (void)ws_size;
  const float* x = (const float*)d_in[0];
  const float* y = (const float*)d_in[1];
  float* out = (float*)d_out;
  char* ws = (char*)d_ws;
  uint16_t* xnb  = (uint16_t*)ws;
  uint16_t* ynb  = (uint16_t*)(ws + (size_t)16777216);
  uint16_t* skew = (uint16_t*)(ws + (size_t)33554432);
  float*  negbuf = (float*)  (ws + (size_t)75497472);
  uint32_t* decg = (uint32_t*)(ws + (size_t)75501568);

  (void)hipFuncSetAttribute((const void*)dtw_fwd_kernel,
                            hipFuncAttributeMaxDynamicSharedMemorySize, 131584);
  (void)hipFuncSetAttribute((const void*)dtw_bt_kernel,
                            hipFuncAttributeMaxDynamicSharedMemorySize, 69632);

  pad_zero_kernel<<<dim3(TT_SKEW, BB), 64, 0, stream>>>(skew);
  norm_cast_kernel<<<16384, 256, 0, stream>>>(x, y, xnb, ynb);
  gemm_cost_kernel<<<1024, 256, 0, stream>>>(xnb, ynb, skew);
  neg_lse_kernel<<<64, 256, 0, stream>>>(skew, negbuf);
  dtw_fwd_kernel<<<32, 64, 131584, stream>>>(skew, decg);
  dtw_bt_kernel<<<64, 64, 69632, stream>>>(skew, decg, negbuf, out);
}

// Round 12
// 365.129 us; speedup vs baseline: 1.1301x; 1.1301x over previous
//
#include <hip/hip_runtime.h>
#include <hip/hip_bf16.h>
#include <stdint.h>

typedef __attribute__((ext_vector_type(8))) short short8v;     // 8 x bf16 (MFMA A/B frag)
typedef __attribute__((ext_vector_type(4))) float float4v;     // MFMA C/D frag / vec loads
typedef __attribute__((ext_vector_type(4))) unsigned short ushort4v;
typedef __attribute__((ext_vector_type(4))) unsigned int uint4v;

#define FINF __builtin_huge_valf()
#define BB 64
#define NN 512
#define DD 256
#define TT_SKEW 640   // skew rows: tau = r + 2*(j>>3) in [0, 511+126] -> pad to 640

// ws layout (bytes):
//   [0,        16777216)  xnb bf16 [B][N][D]
//   [16777216, 33554432)  ynb bf16 [B][N][D]
//   [33554432, 75497472)  cost_skew bf16 [B][640][512] (cell (r,j) at row tau=r+2*(j>>3), col j)
//   [75497472, 75501568)  dump gap (invalid-lane dec stores; write-only, benign races)
//   [75501568, 79695872)  decg u32 [B][16384]  (decision words) — same extent as R8 (proven fits)

static __device__ __forceinline__ unsigned short f2bf(float f) {
  union { float f; uint32_t u; } a; a.f = f;
  uint32_t r = a.u + 0x7fffu + ((a.u >> 16) & 1u);   // RNE
  return (unsigned short)(r >> 16);
}
static __device__ __forceinline__ float bf2f(uint16_t v) {
  return __uint_as_float(((uint32_t)v) << 16);
}

// ---------------- Kernel 1: row-normalize + cast to bf16 ----------------
__global__ __launch_bounds__(256) void norm_cast_kernel(
    const float* __restrict__ x, const float* __restrict__ y,
    uint16_t* __restrict__ xnb, uint16_t* __restrict__ ynb)
{
  const int wave = threadIdx.x >> 6, lane = threadIdx.x & 63;
  const int row = blockIdx.x * 4 + wave;
  const float* src; uint16_t* dst;
  if (row < BB * NN) { src = x + (size_t)row * DD;            dst = xnb + (size_t)row * DD; }
  else               { src = y + (size_t)(row - BB*NN) * DD;  dst = ynb + (size_t)(row - BB*NN) * DD; }
  const float4v v = *(const float4v*)(src + lane * 4);
  float s = v[0]*v[0] + v[1]*v[1] + v[2]*v[2] + v[3]*v[3];
  #pragma unroll
  for (int d = 1; d < 64; d <<= 1) s += __shfl_xor(s, d, 64);
  const float inv = 1.0f / fmaxf(sqrtf(s), 1e-8f);
  ushort4v o;
  o[0] = f2bf(v[0] * inv); o[1] = f2bf(v[1] * inv);
  o[2] = f2bf(v[2] * inv); o[3] = f2bf(v[3] * inv);
  *(ushort4v*)(dst + lane * 4) = o;
}

// ---------------- Kernel 2: cost = 1 - xn·yn -> bf16 skewed layout ----------------
__global__ __launch_bounds__(256) void gemm_cost_kernel(
    const uint16_t* __restrict__ xnb, const uint16_t* __restrict__ ynb,
    uint16_t* __restrict__ skew)
{
  __shared__ uint16_t As[128 * 32];
  __shared__ uint16_t Bs[128 * 32];
  const int bid = blockIdx.x;
  const int b = bid >> 4, tm = (bid >> 2) & 3, tn = bid & 3;
  const int tid = threadIdx.x, wave = tid >> 6, lane = tid & 63;
  const int wr = wave >> 1, wc = wave & 1;

  const char* Ab = (const char*)(xnb + (size_t)b * NN * DD + (size_t)tm * 128 * DD);
  const char* Bb = (const char*)(ynb + (size_t)b * NN * DD + (size_t)tn * 128 * DD);

  float4v acc[4][4];
  #pragma unroll
  for (int i = 0; i < 4; i++)
    #pragma unroll
    for (int j = 0; j < 4; j++) acc[i][j] = (float4v){0.f, 0.f, 0.f, 0.f};

  const int seg0 = wave * 2;
  const int o0 = seg0 * 1024 + lane * 16;
  const int o1 = o0 + 1024;
  const int r0 = o0 >> 6, c0 = o0 & 63;
  const int r1 = o1 >> 6, c1 = o1 & 63;

  for (int kk = 0; kk < 8; kk++) {
    const int kb = kk * 64;
    __builtin_amdgcn_global_load_lds(
        (const __attribute__((address_space(1))) uint32_t*)(Ab + (size_t)r0 * 512 + kb + c0),
        (__attribute__((address_space(3))) uint32_t*)((char*)As + seg0 * 1024), 16, 0, 0);
    __builtin_amdgcn_global_load_lds(
        (const __attribute__((address_space(1))) uint32_t*)(Ab + (size_t)r1 * 512 + kb + c1),
        (__attribute__((address_space(3))) uint32_t*)((char*)As + (seg0 + 1) * 1024), 16, 0, 0);
    __builtin_amdgcn_global_load_lds(
        (const __attribute__((address_space(1))) uint32_t*)(Bb + (size_t)r0 * 512 + kb + c0),
        (__attribute__((address_space(3))) uint32_t*)((char*)Bs + seg0 * 1024), 16, 0, 0);
    __builtin_amdgcn_global_load_lds(
        (const __attribute__((address_space(1))) uint32_t*)(Bb + (size_t)r1 * 512 + kb + c1),
        (__attribute__((address_space(3))) uint32_t*)((char*)Bs + (seg0 + 1) * 1024), 16, 0, 0);
    __syncthreads();

    short8v af[4], bfr[4];
    #pragma unroll
    for (int mi = 0; mi < 4; mi++) {
      const int rr = wr * 64 + mi * 16 + (lane & 15);
      af[mi] = *(const short8v*)((const char*)As + rr * 64 + (lane >> 4) * 16);
    }
    #pragma unroll
    for (int nj = 0; nj < 4; nj++) {
      const int rr = wc * 64 + nj * 16 + (lane & 15);
      bfr[nj] = *(const short8v*)((const char*)Bs + rr * 64 + (lane >> 4) * 16);
    }
    #pragma unroll
    for (int mi = 0; mi < 4; mi++)
      #pragma unroll
      for (int nj = 0; nj < 4; nj++)
        acc[mi][nj] = __builtin_amdgcn_mfma_f32_16x16x32_bf16(af[mi], bfr[nj], acc[mi][nj], 0, 0, 0);
    __syncthreads();
  }

  uint16_t* Cb = skew + (size_t)b * TT_SKEW * NN;
  #pragma unroll
  for (int mi = 0; mi < 4; mi++)
    #pragma unroll
    for (int nj = 0; nj < 4; nj++) {
      const int cc = tn * 128 + wc * 64 + nj * 16 + (lane & 15);
      const int lg = cc >> 3;
      #pragma unroll
      for (int v = 0; v < 4; v++) {
        const int rr = tm * 128 + wr * 64 + mi * 16 + (lane >> 4) * 4 + v;
        Cb[(size_t)(rr + 2 * lg) * NN + cc] = f2bf(1.0f - acc[mi][nj][v]);
      }
    }
}

// ---------------- Kernel 3: DTW forward, 8 independent waves/block ----------------
// Grid 8 x 512thr: wave w = batch blockIdx*8+w; 2 waves/SIMD -> HW interleaves
// two independent batches (TLP; robust against compiler scheduling).
// Loads: asm global_load_dwordx4 with 64-bit VGPR address ("off" form — no
// SGPR saddr, no readfirstlane). Dec words: PLAIN C++ stores (compiler-managed
// addressing/liveness); select on integer address -> cndmask, 1 store/step.
// Waits carry a "memory" clobber so the C++ store is pinned inside its wait
// window; vmcnt arithmetic (3 ops/window: 1 store + 2 loads) is order-proof:
//   prologue 8 loads; peel waits {6,7,8,9}; steady vmcnt(9) retires the whole
//   window(t-4) triple (oldest 3 of <=12) regardless of in-window order.
// Invalid-lane stores go to the ws gap (write-only; races benign).
__global__ __launch_bounds__(512, 2) void dtw_fwd_kernel(
    const uint16_t* __restrict__ skew, uint32_t* __restrict__ decg,
    uint32_t* __restrict__ dumpg)
{
  const int tid = threadIdx.x;
  const int wv = tid >> 6, l = tid & 63;
  const int batch = blockIdx.x * 8 + wv;
  const uint16_t* csk = skew + (size_t)batch * TT_SKEW * NN;
  uint32_t* const dw = decg + (size_t)batch * 16384;
  const uintptr_t dmp_addr = (uintptr_t)(dumpg + l);
  const uint64_t base64 = (uint64_t)(uintptr_t)csk + 16u * (uint32_t)l;
  const bool is0 = (l == 0);

  uint4v rA[4], rB[4];
  #pragma unroll
  for (int i = 0; i < 4; ++i) {
    const uint64_t aA = base64 + ((uint64_t)(2 * i) << 10);
    asm volatile("global_load_dwordx4 %0, %1, off" : "=v"(rA[i]) : "v"(aA));
    asm volatile("global_load_dwordx4 %0, %1, off" : "=v"(rB[i]) : "v"(aA + 1024u));
  }

  float tp[8];
  #pragma unroll
  for (int c = 0; c < 8; ++c) tp[c] = FINF;
  float cl0 = FINF, cl1 = FINF, carry = FINF;

  auto STEP = [&](int t, const uint4v A, const uint4v Bv) {
    float shA = __shfl_up(cl0, 1, 64);   // tc[r0][8l-1]
    float shB = __shfl_up(cl1, 1, 64);   // tc[r1][8l-1]
    if (is0) { shA = (t == 0) ? 0.0f : FINF; shB = FINF; }
    const float sh_p0 = carry;            // tc[r0-1][8l-1]
    carry = shB;
    const float shA1 = is0 ? FINF : shA;  // row1 diag col0 (INF at l=0)

    const uint32_t rlane = (uint32_t)(t - l);
    const bool valid = rlane < 256u;

    float ca[8], cb[8], S0[8], S1[8];
    #pragma unroll
    for (int k = 0; k < 4; ++k) {
      ca[2*k]   = __uint_as_float(A[k] << 16);
      ca[2*k+1] = __uint_as_float(A[k] & 0xFFFF0000u);
      cb[2*k]   = __uint_as_float(Bv[k] << 16);
      cb[2*k+1] = __uint_as_float(Bv[k] & 0xFFFF0000u);
    }
    S0[0] = ca[0]; S1[0] = cb[0];
    #pragma unroll
    for (int c = 1; c < 8; ++c) { S0[c] = S0[c-1] + ca[c]; S1[c] = S1[c-1] + cb[c]; }

    // row 0
    float dcp0[8], mu0[8], w0[8], PW0[8], tn0[8];
    dcp0[0] = sh_p0;
    #pragma unroll
    for (int c = 1; c < 8; ++c) dcp0[c] = tp[c-1];
    #pragma unroll
    for (int c = 0; c < 8; ++c) mu0[c] = fminf(dcp0[c], tp[c]);
    w0[0] = mu0[0];
    #pragma unroll
    for (int c = 1; c < 8; ++c) w0[c] = mu0[c] - S0[c-1];
    PW0[0] = w0[0];
    #pragma unroll
    for (int c = 1; c < 8; ++c) PW0[c] = fminf(PW0[c-1], w0[c]);
    #pragma unroll
    for (int c = 0; c < 8; ++c) tn0[c] = fminf(PW0[c], shA) + S0[c];

    // row 1 (chains on row 0 in-lane)
    float dcp1[8], mu1[8], w1[8], PW1[8], tn1[8];
    dcp1[0] = shA1;
    #pragma unroll
    for (int c = 1; c < 8; ++c) dcp1[c] = tn0[c-1];
    #pragma unroll
    for (int c = 0; c < 8; ++c) mu1[c] = fminf(dcp1[c], tn0[c]);
    w1[0] = mu1[0];
    #pragma unroll
    for (int c = 1; c < 8; ++c) w1[c] = mu1[c] - S1[c-1];
    PW1[0] = w1[0];
    #pragma unroll
    for (int c = 1; c < 8; ++c) PW1[c] = fminf(PW1[c-1], w1[c]);
    #pragma unroll
    for (int c = 0; c < 8; ++c) tn1[c] = fminf(PW1[c], shB) + S1[c];

    // decisions (ref tie-break diag > up > left): dd=(lc<mu)?2:(up<dcp)
    uint32_t word = 0;
    {
      float lc0[8], lc1[8];
      lc0[0] = shA; lc1[0] = shB;
      #pragma unroll
      for (int c = 1; c < 8; ++c) { lc0[c] = tn0[c-1]; lc1[c] = tn1[c-1]; }
      #pragma unroll
      for (int c = 0; c < 8; ++c) {
        const uint32_t e0 = (tp[c] < dcp0[c]) ? 1u : 0u;
        const uint32_t d0 = (lc0[c] < mu0[c]) ? 2u : e0;
        const uint32_t e1 = (tn0[c] < dcp1[c]) ? 1u : 0u;
        const uint32_t d1 = (lc1[c] < mu1[c]) ? 2u : e1;
        word |= (d0 << (2 * c)) | (d1 << (16 + 2 * c));
      }
    }
    // plain C++ store; integer-address select -> cndmask + 1 global_store_dword
    const uintptr_t dsta = valid ? (uintptr_t)(dw + (rlane << 6) + l) : dmp_addr;
    *(uint32_t*)dsta = word;

    #pragma unroll
    for (int c = 0; c < 8; ++c) tp[c] = valid ? tn1[c] : tp[c];
    cl0 = valid ? tn0[7] : cl0;
    cl1 = tp[7];
  };

  auto RELOAD = [&](int u, int t) {  // rows 2(t+4), +1 (clamped; always 2 loads)
    int rr = 2 * (t + 4); if (rr > 638) rr = 638;
    const uint64_t aA = base64 + ((uint64_t)rr << 10);
    asm volatile("global_load_dwordx4 %0, %1, off" : "=v"(rA[u]) : "v"(aA));
    asm volatile("global_load_dwordx4 %0, %1, off" : "=v"(rB[u]) : "v"(aA + 1024u));
  };

  // peeled first 4 steps: exact prologue vmcnt counts {6,7,8,9}
  asm volatile("s_waitcnt vmcnt(6)" : "+v"(rA[0]), "+v"(rB[0]) : : "memory");
  STEP(0, rA[0], rB[0]); RELOAD(0, 0);
  asm volatile("s_waitcnt vmcnt(7)" : "+v"(rA[1]), "+v"(rB[1]) : : "memory");
  STEP(1, rA[1], rB[1]); RELOAD(1, 1);
  asm volatile("s_waitcnt vmcnt(8)" : "+v"(rA[2]), "+v"(rB[2]) : : "memory");
  STEP(2, rA[2], rB[2]); RELOAD(2, 2);
  asm volatile("s_waitcnt vmcnt(9)" : "+v"(rA[3]), "+v"(rB[3]) : : "memory");
  STEP(3, rA[3], rB[3]); RELOAD(3, 3);

  for (int t0 = 4; t0 < 320; t0 += 4) {
    #pragma unroll
    for (int u = 0; u < 4; ++u) {
      const int t = t0 + u;
      // retires window(t-4)'s triple {store, loadA, loadB} -> ring slot u ready
      asm volatile("s_waitcnt vmcnt(9)" : "+v"(rA[u]), "+v"(rB[u]) : : "memory");
      STEP(t, rA[u], rB[u]);
      RELOAD(u, t);
    }
  }
  asm volatile("s_waitcnt vmcnt(0)" ::: "memory");
}

// ---------------- Kernel 4: neg LSE + backtrack + colpos + pos LSE ----------------
// 64 blocks x 256 thr. dec word [rp][l]: rows {2rp,2rp+1}, cols [8l,8l+8),
// bit = (i&1)*16 + (j&7)*2. Region walk: 4x8 region = 2 words, walk in regs.
__global__ __launch_bounds__(256, 1) void dtw_bt_kernel(
    const uint16_t* __restrict__ skew, const uint32_t* __restrict__ decg,
    float* __restrict__ out)
{
  extern __shared__ char lds_raw[];
  uint16_t* rlo    = (uint16_t*)(lds_raw + 65536);
  uint16_t* rhi    = (uint16_t*)(lds_raw + 66560);
  float*    colpos = (float*)  (lds_raw + 67584);
  float*    sm     = (float*)  (lds_raw + 69632);   // [8]
  const uint32_t* dec32 = (const uint32_t*)lds_raw;

  const int tid = threadIdx.x, wave = tid >> 6, lane = tid & 63;
  const int b = blockIdx.x;
  const uint16_t* csk = skew + (size_t)b * TT_SKEW * NN;
  const uint32_t* dg = decg + (size_t)b * 16384;

  // copy dec 64KB -> LDS (256 thr x 16B x 16 iters)
  #pragma unroll
  for (int i = 0; i < 16; ++i)
    *(uint4v*)(lds_raw + i * 4096 + tid * 16) = *(const uint4v*)(dg + i * 1024 + tid * 4);
  for (int r = tid; r < NN; r += 256) { rlo[r] = 1; rhi[r] = 0; colpos[r] = 0.0f; }

  // ---- neg: thread sums cols {2tid, 2tid+1} over the 512 valid skew rows ----
  const int g = tid >> 2;
  const uint32_t* p = (const uint32_t*)csk + (size_t)(2 * g) * 256 + tid;
  float s0 = 0.f, s1 = 0.f;
  #pragma unroll 8
  for (int t = 0; t < 512; ++t) {
    const uint32_t w = p[(size_t)t * 256];
    s0 += __uint_as_float(w << 16);
    s1 += __uint_as_float(w & 0xFFFF0000u);
  }
  float m = fmaxf(s0, s1);
  #pragma unroll
  for (int d = 1; d < 64; d <<= 1) m = fmaxf(m, __shfl_xor(m, d, 64));
  if (lane == 0) sm[wave] = m;
  __syncthreads();
  m = fmaxf(fmaxf(sm[0], sm[1]), fmaxf(sm[2], sm[3]));
  float e = expf(s0 - m) + expf(s1 - m);
  #pragma unroll
  for (int d = 1; d < 64; d <<= 1) e += __shfl_xor(e, d, 64);
  if (lane == 0) sm[4 + wave] = e;
  __syncthreads();
  const float neg = m + logf(sm[4] + sm[5] + sm[6] + sm[7]);
  __syncthreads();

  // ---- backtrack (tid 0): region-cached walk ----
  if (tid == 0) {
    int i = NN - 1, j = NN - 1, hicur = NN - 1;
    while (i > 0 && j > 0) {
      const int a = i >> 2, g2 = j >> 3;
      const uint32_t w0 = dec32[a * 128 + g2];        // rows 4a,4a+1
      const uint32_t w1 = dec32[a * 128 + 64 + g2];   // rows 4a+2,4a+3
      const int ilo = a << 2, jlo = g2 << 3;
      while (i >= ilo && j >= jlo && i > 0 && j > 0) {
        const uint32_t w = (i & 2) ? w1 : w0;
        const uint32_t dd = (w >> (((i & 1) << 4) + ((j & 7) << 1))) & 3u;
        if (dd == 2u) { j--; }           // left: stay in row
        else {
          rlo[i] = (uint16_t)j; rhi[i] = (uint16_t)hicur;  // leave row i
          i--;
          if (dd == 0u) j--;             // diag also moves left
          hicur = j;                     // entry column of new row
        }
      }
    }
    rlo[i] = (uint16_t)j; rhi[i] = (uint16_t)hicur;      // pending row at exit
  }
  __syncthreads();

  // ---- colpos: 2 rows per thread ----
  for (int r = tid; r < NN; r += 256) {
    const int lo = rlo[r], hi = rhi[r];
    for (int j = lo; j <= hi; j++) {
      const float cv = bf2f(csk[(size_t)(r + 2 * (j >> 3)) * NN + j]);
      atomicAdd(&colpos[j], cv);
    }
  }
  if (tid == 0 && rlo[0] != 0) atomicAdd(&colpos[0], bf2f(csk[0]));
  __syncthreads();

  // ---- pos = LSE over colpos[512] with 256 threads ----
  const float mv0 = colpos[tid], mv1 = colpos[tid + 256];
  float mx = fmaxf(mv0, mv1);
  #pragma unroll
  for (int d = 1; d < 64; d <<= 1) mx = fmaxf(mx, __shfl_xor(mx, d, 64));
  if (lane == 0) sm[wave] = mx;
  __syncthreads();
  mx = fmaxf(fmaxf(sm[0], sm[1]), fmaxf(sm[2], sm[3]));
  float e2 = expf(mv0 - mx) + expf(mv1 - mx);
  #pragma unroll
  for (int d = 1; d < 64; d <<= 1) e2 += __shfl_xor(e2, d, 64);
  if (lane == 0) sm[4 + wave] = e2;
  __syncthreads();
  if (tid == 0) out[b] = mx + logf(sm[4] + sm[5] + sm[6] + sm[7]) - neg;
}

extern "C" void kernel_launch(void* const* d_in, const int* in_sizes, int n_in,
                              void* d_out, int out_size, void* d_ws, size_t ws_size,
                              hipStream_t stream)
{
  (void)in_sizes; (void)n_in; (void)out_size; (void)ws_size;
  const float* x = (const float*)d_in[0];
  const float* y = (const float*)d_in[1];
  float* out = (float*)d_out;
  char* ws = (char*)d_ws;
  uint16_t* xnb  = (uint16_t*)ws;
  uint16_t* ynb  = (uint16_t*)(ws + (size_t)16777216);
  uint16_t* skew = (uint16_t*)(ws + (size_t)33554432);
  uint32_t* dumpg = (uint32_t*)(ws + (size_t)75497472);
  uint32_t* decg  = (uint32_t*)(ws + (size_t)75501568);

  (void)hipFuncSetAttribute((const void*)dtw_bt_kernel,
                            hipFuncAttributeMaxDynamicSharedMemorySize, 69760);

  norm_cast_kernel<<<16384, 256, 0, stream>>>(x, y, xnb, ynb);
  gemm_cost_kernel<<<1024, 256, 0, stream>>>(xnb, ynb, skew);
  dtw_fwd_kernel<<<8, 512, 0, stream>>>(skew, decg, dumpg);
  dtw_bt_kernel<<<64, 256, 69760, stream>>>(skew, decg, out);
}

// Round 13
// 285.614 us; speedup vs baseline: 1.4447x; 1.2784x over previous
//
#include <hip/hip_runtime.h>
#include <hip/hip_bf16.h>
#include <stdint.h>

typedef __attribute__((ext_vector_type(8))) short short8v;     // 8 x bf16 (MFMA A/B frag)
typedef __attribute__((ext_vector_type(4))) float float4v;     // MFMA C/D frag / vec loads
typedef __attribute__((ext_vector_type(4))) unsigned short ushort4v;
typedef __attribute__((ext_vector_type(4))) unsigned int uint4v;

#define FINF __builtin_huge_valf()
#define BB 64
#define NN 512
#define DD 256
#define TT_SKEW 768   // skew rows: tau = r + 4*(j>>3) in [0, 511+252] -> pad to 768

// ws layout (bytes):
//   [0,        16777216)  xnb bf16 [B][N][D]
//   [16777216, 33554432)  ynb bf16 [B][N][D]
//   [33554432, 83886080)  cost_skew bf16 [B][768][512] (cell (r,j) at row tau=r+4*(j>>3), col j)
//   [83886080, 84017152)  colsum f32 [B][512] (column sums of cost, from GEMM epilogue)
//   [84017152, 84021248)  dump gap (invalid-lane dec stores; write-only)
//   [84021248, 88215552)  decg u32 [B][16384]

static __device__ __forceinline__ unsigned short f2bf(float f) {
  union { float f; uint32_t u; } a; a.f = f;
  uint32_t r = a.u + 0x7fffu + ((a.u >> 16) & 1u);   // RNE
  return (unsigned short)(r >> 16);
}
static __device__ __forceinline__ float bf2f(uint16_t v) {
  return __uint_as_float(((uint32_t)v) << 16);
}

// ---------------- Kernel 0: zero the colsum buffer ----------------
__global__ __launch_bounds__(256) void zero_colsum_kernel(float* __restrict__ colsum)
{
  colsum[blockIdx.x * 256 + threadIdx.x] = 0.0f;
}

// ---------------- Kernel 1: row-normalize + cast to bf16 ----------------
__global__ __launch_bounds__(256) void norm_cast_kernel(
    const float* __restrict__ x, const float* __restrict__ y,
    uint16_t* __restrict__ xnb, uint16_t* __restrict__ ynb)
{
  const int wave = threadIdx.x >> 6, lane = threadIdx.x & 63;
  const int row = blockIdx.x * 4 + wave;
  const float* src; uint16_t* dst;
  if (row < BB * NN) { src = x + (size_t)row * DD;            dst = xnb + (size_t)row * DD; }
  else               { src = y + (size_t)(row - BB*NN) * DD;  dst = ynb + (size_t)(row - BB*NN) * DD; }
  const float4v v = *(const float4v*)(src + lane * 4);
  float s = v[0]*v[0] + v[1]*v[1] + v[2]*v[2] + v[3]*v[3];
  #pragma unroll
  for (int d = 1; d < 64; d <<= 1) s += __shfl_xor(s, d, 64);
  const float inv = 1.0f / fmaxf(sqrtf(s), 1e-8f);
  ushort4v o;
  o[0] = f2bf(v[0] * inv); o[1] = f2bf(v[1] * inv);
  o[2] = f2bf(v[2] * inv); o[3] = f2bf(v[3] * inv);
  *(ushort4v*)(dst + lane * 4) = o;
}

// ---------------- Kernel 2: cost = 1 - xn·yn -> bf16 skew + colsum atomics ----------------
__global__ __launch_bounds__(256) void gemm_cost_kernel(
    const uint16_t* __restrict__ xnb, const uint16_t* __restrict__ ynb,
    uint16_t* __restrict__ skew, float* __restrict__ colsum)
{
  __shared__ uint16_t As[128 * 32];
  __shared__ uint16_t Bs[128 * 32];
  const int bid = blockIdx.x;
  const int b = bid >> 4, tm = (bid >> 2) & 3, tn = bid & 3;
  const int tid = threadIdx.x, wave = tid >> 6, lane = tid & 63;
  const int wr = wave >> 1, wc = wave & 1;

  const char* Ab = (const char*)(xnb + (size_t)b * NN * DD + (size_t)tm * 128 * DD);
  const char* Bb = (const char*)(ynb + (size_t)b * NN * DD + (size_t)tn * 128 * DD);

  float4v acc[4][4];
  #pragma unroll
  for (int i = 0; i < 4; i++)
    #pragma unroll
    for (int j = 0; j < 4; j++) acc[i][j] = (float4v){0.f, 0.f, 0.f, 0.f};

  const int seg0 = wave * 2;
  const int o0 = seg0 * 1024 + lane * 16;
  const int o1 = o0 + 1024;
  const int r0 = o0 >> 6, c0 = o0 & 63;
  const int r1 = o1 >> 6, c1 = o1 & 63;

  for (int kk = 0; kk < 8; kk++) {
    const int kb = kk * 64;
    __builtin_amdgcn_global_load_lds(
        (const __attribute__((address_space(1))) uint32_t*)(Ab + (size_t)r0 * 512 + kb + c0),
        (__attribute__((address_space(3))) uint32_t*)((char*)As + seg0 * 1024), 16, 0, 0);
    __builtin_amdgcn_global_load_lds(
        (const __attribute__((address_space(1))) uint32_t*)(Ab + (size_t)r1 * 512 + kb + c1),
        (__attribute__((address_space(3))) uint32_t*)((char*)As + (seg0 + 1) * 1024), 16, 0, 0);
    __builtin_amdgcn_global_load_lds(
        (const __attribute__((address_space(1))) uint32_t*)(Bb + (size_t)r0 * 512 + kb + c0),
        (__attribute__((address_space(3))) uint32_t*)((char*)Bs + seg0 * 1024), 16, 0, 0);
    __builtin_amdgcn_global_load_lds(
        (const __attribute__((address_space(1))) uint32_t*)(Bb + (size_t)r1 * 512 + kb + c1),
        (__attribute__((address_space(3))) uint32_t*)((char*)Bs + (seg0 + 1) * 1024), 16, 0, 0);
    __syncthreads();

    short8v af[4], bfr[4];
    #pragma unroll
    for (int mi = 0; mi < 4; mi++) {
      const int rr = wr * 64 + mi * 16 + (lane & 15);
      af[mi] = *(const short8v*)((const char*)As + rr * 64 + (lane >> 4) * 16);
    }
    #pragma unroll
    for (int nj = 0; nj < 4; nj++) {
      const int rr = wc * 64 + nj * 16 + (lane & 15);
      bfr[nj] = *(const short8v*)((const char*)Bs + rr * 64 + (lane >> 4) * 16);
    }
    #pragma unroll
    for (int mi = 0; mi < 4; mi++)
      #pragma unroll
      for (int nj = 0; nj < 4; nj++)
        acc[mi][nj] = __builtin_amdgcn_mfma_f32_16x16x32_bf16(af[mi], bfr[nj], acc[mi][nj], 0, 0, 0);
    __syncthreads();
  }

  uint16_t* Cb = skew + (size_t)b * TT_SKEW * NN;
  #pragma unroll
  for (int mi = 0; mi < 4; mi++)
    #pragma unroll
    for (int nj = 0; nj < 4; nj++) {
      const int cc = tn * 128 + wc * 64 + nj * 16 + (lane & 15);
      const int lg = cc >> 3;
      #pragma unroll
      for (int v = 0; v < 4; v++) {
        const int rr = tm * 128 + wr * 64 + mi * 16 + (lane >> 4) * 4 + v;
        Cb[(size_t)(rr + 4 * lg) * NN + cc] = f2bf(1.0f - acc[mi][nj][v]);
      }
    }

  // column-sum partials (for neg LSE): sum cost over this wave's 64 rows
  #pragma unroll
  for (int nj = 0; nj < 4; nj++) {
    const int cc = tn * 128 + wc * 64 + nj * 16 + (lane & 15);
    float s = 0.f;
    #pragma unroll
    for (int mi = 0; mi < 4; mi++)
      #pragma unroll
      for (int v = 0; v < 4; v++) s += 1.0f - acc[mi][nj][v];
    s += __shfl_xor(s, 16, 64);
    s += __shfl_xor(s, 32, 64);
    if (lane < 16) atomicAdd(&colsum[b * 512 + cc], s);
  }
}

// ---------------- Kernel 3: DTW forward, 4 rows/lane/step ----------------
// 64 blocks x 1 wave (R8 config: 64 CUs, 1 wave each — R12 proved TLP
// concentration loses). Lane l owns cols [8l,8l+8); step t does rows
// 4(t-l)..4(t-l)+3 — 192 steps (vs R8's 320) amortizing the measured fixed
// ~590cy/step overhead over 2x work. Skew tau=r+4*(j>>3) -> 4 contiguous 1KB
// row loads/step. 4-deep x 4-row register ring (asm loads, 64-bit vaddr);
// dec words via plain C++ stores (R12-proven); vmcnt 6 ops/step: peel
// {12,14,16,18}, steady 18. Boundary via 4 masked cl regs + 4 shfl_up
// (single DS round; masking makes pre/post-validity exact — R8-proven).
__global__ __launch_bounds__(64, 1) void dtw_fwd_kernel(
    const uint16_t* __restrict__ skew, uint32_t* __restrict__ decg,
    uint32_t* __restrict__ dumpg)
{
  const int l = threadIdx.x;
  const int b = blockIdx.x;
  const uint16_t* csk = skew + (size_t)b * TT_SKEW * NN;
  uint32_t* const dw = decg + (size_t)b * 16384;
  const uint64_t base64 = (uint64_t)(uintptr_t)csk + 16u * (uint32_t)l;
  const bool is0 = (l == 0);

  uint4v rg[4][4];                       // [slot][row-in-step]
  #pragma unroll
  for (int i = 0; i < 4; ++i)
    #pragma unroll
    for (int k = 0; k < 4; ++k) {
      const uint64_t a = base64 + ((uint64_t)(4 * i + k) << 10);
      asm volatile("global_load_dwordx4 %0, %1, off" : "=v"(rg[i][k]) : "v"(a));
    }

  float tp[8];
  #pragma unroll
  for (int c = 0; c < 8; ++c) tp[c] = FINF;
  float cl0 = FINF, cl1 = FINF, cl2 = FINF, cl3 = FINF, carry = FINF;

  auto UNPACK = [&](const uint4v R, float (&S)[8]) {
    const float a0 = __uint_as_float(R[0] << 16);
    const float a1 = __uint_as_float(R[0] & 0xFFFF0000u);
    const float a2 = __uint_as_float(R[1] << 16);
    const float a3 = __uint_as_float(R[1] & 0xFFFF0000u);
    const float a4 = __uint_as_float(R[2] << 16);
    const float a5 = __uint_as_float(R[2] & 0xFFFF0000u);
    const float a6 = __uint_as_float(R[3] << 16);
    const float a7 = __uint_as_float(R[3] & 0xFFFF0000u);
    S[0] = a0; S[1] = S[0] + a1; S[2] = S[1] + a2; S[3] = S[2] + a3;
    S[4] = S[3] + a4; S[5] = S[4] + a5; S[6] = S[5] + a6; S[7] = S[6] + a7;
  };

  // One DP row: up[] holds previous row's tc in, this row's tc out.
  auto ROW = [&](const float (&S)[8], float (&up)[8], float leftv, float diag0,
                 uint32_t &word, int sh) {
    float dcp[8], mu[8], w[8], PW[8], tn[8];
    dcp[0] = diag0;
    #pragma unroll
    for (int c = 1; c < 8; ++c) dcp[c] = up[c - 1];
    #pragma unroll
    for (int c = 0; c < 8; ++c) mu[c] = fminf(dcp[c], up[c]);
    w[0] = mu[0];
    #pragma unroll
    for (int c = 1; c < 8; ++c) w[c] = mu[c] - S[c - 1];
    PW[0] = w[0];
    #pragma unroll
    for (int c = 1; c < 8; ++c) PW[c] = fminf(PW[c - 1], w[c]);
    #pragma unroll
    for (int c = 0; c < 8; ++c) tn[c] = fminf(PW[c], leftv) + S[c];
    float lc[8];
    lc[0] = leftv;
    #pragma unroll
    for (int c = 1; c < 8; ++c) lc[c] = tn[c - 1];
    #pragma unroll
    for (int c = 0; c < 8; ++c) {
      // tie-break diag > up > left (== reference equality chain)
      const uint32_t e = (up[c] < dcp[c]) ? 1u : 0u;
      const uint32_t d = (lc[c] < mu[c]) ? 2u : e;
      word |= d << (sh + 2 * c);
    }
    #pragma unroll
    for (int c = 0; c < 8; ++c) up[c] = tn[c];
  };

  auto STEP = [&](int t, const uint4v R0, const uint4v R1,
                  const uint4v R2, const uint4v R3) {
    // 4 back-to-back shuffles -> one DS round
    const float s0r = __shfl_up(cl0, 1, 64);
    const float s1r = __shfl_up(cl1, 1, 64);
    const float s2r = __shfl_up(cl2, 1, 64);
    const float s3r = __shfl_up(cl3, 1, 64);
    float S0[8], S1[8], S2[8], S3[8];
    UNPACK(R0, S0); UNPACK(R1, S1); UNPACK(R2, S2); UNPACK(R3, S3);
    const float sh0 = is0 ? ((t == 0) ? 0.0f : FINF) : s0r;  // left, row0
    const float sh1 = is0 ? FINF : s1r;
    const float sh2 = is0 ? FINF : s2r;
    const float sh3 = is0 ? FINF : s3r;
    const float dgA = carry;                 // diag col0, row0 = prev step's sh3
    const float dg1 = is0 ? FINF : s0r;      // diag col0, row k = sh_{k-1}
    const float dg2 = is0 ? FINF : s1r;
    const float dg3 = is0 ? FINF : s2r;
    carry = sh3;

    const uint32_t a = (uint32_t)(t - l);
    const bool valid = a < 128u;

    float up[8];
    #pragma unroll
    for (int c = 0; c < 8; ++c) up[c] = tp[c];
    uint32_t w0 = 0, w1 = 0;
    ROW(S0, up, sh0, dgA, w0, 0);  const float h0 = up[7];
    ROW(S1, up, sh1, dg1, w0, 16); const float h1 = up[7];
    ROW(S2, up, sh2, dg2, w1, 0);  const float h2 = up[7];
    ROW(S3, up, sh3, dg3, w1, 16); const float h3 = up[7];

    uint32_t* p0 = valid ? (dw + (a << 7) + l) : (dumpg + l);
    uint32_t* p1 = valid ? (dw + (a << 7) + 64 + l) : (dumpg + 64 + l);
    *p0 = w0; *p1 = w1;

    #pragma unroll
    for (int c = 0; c < 8; ++c) tp[c] = valid ? up[c] : tp[c];
    cl0 = valid ? h0 : cl0;
    cl1 = valid ? h1 : cl1;
    cl2 = valid ? h2 : cl2;
    cl3 = valid ? h3 : cl3;
  };

  auto RELOAD = [&](int u, int t) {   // rows 4(t+4)..+3, clamped in-bounds
    int rr = 4 * (t + 4); if (rr > 764) rr = 764;
    #pragma unroll
    for (int k = 0; k < 4; ++k) {
      const uint64_t a = base64 + ((uint64_t)(rr + k) << 10);
      asm volatile("global_load_dwordx4 %0, %1, off" : "=v"(rg[u][k]) : "v"(a));
    }
  };

  // peeled first 4 steps: prologue 16 loads -> vmcnt {12,14,16,18}
  asm volatile("s_waitcnt vmcnt(12)"
               : "+v"(rg[0][0]), "+v"(rg[0][1]), "+v"(rg[0][2]), "+v"(rg[0][3]) : : "memory");
  STEP(0, rg[0][0], rg[0][1], rg[0][2], rg[0][3]); RELOAD(0, 0);
  asm volatile("s_waitcnt vmcnt(14)"
               : "+v"(rg[1][0]), "+v"(rg[1][1]), "+v"(rg[1][2]), "+v"(rg[1][3]) : : "memory");
  STEP(1, rg[1][0], rg[1][1], rg[1][2], rg[1][3]); RELOAD(1, 1);
  asm volatile("s_waitcnt vmcnt(16)"
               : "+v"(rg[2][0]), "+v"(rg[2][1]), "+v"(rg[2][2]), "+v"(rg[2][3]) : : "memory");
  STEP(2, rg[2][0], rg[2][1], rg[2][2], rg[2][3]); RELOAD(2, 2);
  asm volatile("s_waitcnt vmcnt(18)"
               : "+v"(rg[3][0]), "+v"(rg[3][1]), "+v"(rg[3][2]), "+v"(rg[3][3]) : : "memory");
  STEP(3, rg[3][0], rg[3][1], rg[3][2], rg[3][3]); RELOAD(3, 3);

  for (int t0 = 4; t0 < 192; t0 += 4) {
    #pragma unroll
    for (int u = 0; u < 4; ++u) {
      const int t = t0 + u;
      // retires window(t-4)'s 6 ops {2 stores, 4 loads} -> slot u ready
      asm volatile("s_waitcnt vmcnt(18)"
                   : "+v"(rg[u][0]), "+v"(rg[u][1]), "+v"(rg[u][2]), "+v"(rg[u][3]) : : "memory");
      STEP(t, rg[u][0], rg[u][1], rg[u][2], rg[u][3]);
      RELOAD(u, t);
    }
  }
  asm volatile("s_waitcnt vmcnt(0)" ::: "memory");
}

// ---------------- Kernel 4: neg LSE (from colsum) + backtrack + colpos + pos LSE ----
// 64 blocks x 256 thr. dec word pair per (a = i>>2, g = j>>3): w0 rows 4a..4a+1
// at dec32[a*128+g], w1 rows 4a+2..4a+3 at dec32[a*128+64+g]; bit =
// (i&1)*16 + (j&7)*2. Region walk in registers.
__global__ __launch_bounds__(256, 1) void dtw_bt_kernel(
    const uint16_t* __restrict__ skew, const uint32_t* __restrict__ decg,
    const float* __restrict__ colsum, float* __restrict__ out)
{
  extern __shared__ char lds_raw[];
  uint16_t* rlo    = (uint16_t*)(lds_raw + 65536);
  uint16_t* rhi    = (uint16_t*)(lds_raw + 66560);
  float*    colpos = (float*)  (lds_raw + 67584);
  float*    sm     = (float*)  (lds_raw + 69632);   // [8]
  const uint32_t* dec32 = (const uint32_t*)lds_raw;

  const int tid = threadIdx.x, wave = tid >> 6, lane = tid & 63;
  const int b = blockIdx.x;
  const uint16_t* csk = skew + (size_t)b * TT_SKEW * NN;
  const uint32_t* dg = decg + (size_t)b * 16384;

  // copy dec 64KB -> LDS
  #pragma unroll
  for (int i = 0; i < 16; ++i)
    *(uint4v*)(lds_raw + i * 4096 + tid * 16) = *(const uint4v*)(dg + i * 1024 + tid * 4);
  for (int r = tid; r < NN; r += 256) { rlo[r] = 1; rhi[r] = 0; colpos[r] = 0.0f; }

  // ---- neg = LSE over colsum[b][0..511] ----
  const float* cs = colsum + (size_t)b * 512;
  const float n0 = cs[tid], n1 = cs[tid + 256];
  float m = fmaxf(n0, n1);
  #pragma unroll
  for (int d = 1; d < 64; d <<= 1) m = fmaxf(m, __shfl_xor(m, d, 64));
  if (lane == 0) sm[wave] = m;
  __syncthreads();
  m = fmaxf(fmaxf(sm[0], sm[1]), fmaxf(sm[2], sm[3]));
  float e = expf(n0 - m) + expf(n1 - m);
  #pragma unroll
  for (int d = 1; d < 64; d <<= 1) e += __shfl_xor(e, d, 64);
  if (lane == 0) sm[4 + wave] = e;
  __syncthreads();
  const float neg = m + logf(sm[4] + sm[5] + sm[6] + sm[7]);
  __syncthreads();

  // ---- backtrack (tid 0): region-cached walk ----
  if (tid == 0) {
    int i = NN - 1, j = NN - 1, hicur = NN - 1;
    while (i > 0 && j > 0) {
      const int a = i >> 2, g2 = j >> 3;
      const uint32_t w0 = dec32[a * 128 + g2];        // rows 4a,4a+1
      const uint32_t w1 = dec32[a * 128 + 64 + g2];   // rows 4a+2,4a+3
      const int ilo = a << 2, jlo = g2 << 3;
      while (i >= ilo && j >= jlo && i > 0 && j > 0) {
        const uint32_t w = (i & 2) ? w1 : w0;
        const uint32_t dd = (w >> (((i & 1) << 4) + ((j & 7) << 1))) & 3u;
        if (dd == 2u) { j--; }           // left: stay in row
        else {
          rlo[i] = (uint16_t)j; rhi[i] = (uint16_t)hicur;  // leave row i
          i--;
          if (dd == 0u) j--;             // diag also moves left
          hicur = j;                     // entry column of new row
        }
      }
    }
    rlo[i] = (uint16_t)j; rhi[i] = (uint16_t)hicur;      // pending row at exit
  }
  __syncthreads();

  // ---- colpos: 2 rows per thread (4-row skew addressing) ----
  for (int r = tid; r < NN; r += 256) {
    const int lo = rlo[r], hi = rhi[r];
    for (int j = lo; j <= hi; j++) {
      const float cv = bf2f(csk[(size_t)(r + 4 * (j >> 3)) * NN + j]);
      atomicAdd(&colpos[j], cv);
    }
  }
  if (tid == 0 && rlo[0] != 0) atomicAdd(&colpos[0], bf2f(csk[0]));
  __syncthreads();

  // ---- pos = LSE over colpos[512] ----
  const float mv0 = colpos[tid], mv1 = colpos[tid + 256];
  float mx = fmaxf(mv0, mv1);
  #pragma unroll
  for (int d = 1; d < 64; d <<= 1) mx = fmaxf(mx, __shfl_xor(mx, d, 64));
  if (lane == 0) sm[wave] = mx;
  __syncthreads();
  mx = fmaxf(fmaxf(sm[0], sm[1]), fmaxf(sm[2], sm[3]));
  float e2 = expf(mv0 - mx) + expf(mv1 - mx);
  #pragma unroll
  for (int d = 1; d < 64; d <<= 1) e2 += __shfl_xor(e2, d, 64);
  if (lane == 0) sm[4 + wave] = e2;
  __syncthreads();
  if (tid == 0) out[b] = mx + logf(sm[4] + sm[5] + sm[6] + sm[7]) - neg;
}

extern "C" void kernel_launch(void* const* d_in, const int* in_sizes, int n_in,
                              void* d_out, int out_size, void* d_ws, size_t ws_size,
                              hipStream_t stream)
{
  (void)in_sizes; (void)n_in; (void)out_size; (void)ws_size;
  const float* x = (const float*)d_in[0];
  const float* y = (const float*)d_in[1];
  float* out = (float*)d_out;
  char* ws = (char*)d_ws;
  uint16_t* xnb   = (uint16_t*)ws;
  uint16_t* ynb   = (uint16_t*)(ws + (size_t)16777216);
  uint16_t* skew  = (uint16_t*)(ws + (size_t)33554432);
  float*   colsum = (float*)   (ws + (size_t)83886080);
  uint32_t* dumpg = (uint32_t*)(ws + (size_t)84017152);
  uint32_t* decg  = (uint32_t*)(ws + (size_t)84021248);

  (void)hipFuncSetAttribute((const void*)dtw_bt_kernel,
                            hipFuncAttributeMaxDynamicSharedMemorySize, 69760);

  zero_colsum_kernel<<<128, 256, 0, stream>>>(colsum);
  norm_cast_kernel<<<16384, 256, 0, stream>>>(x, y, xnb, ynb);
  gemm_cost_kernel<<<1024, 256, 0, stream>>>(xnb, ynb, skew, colsum);
  dtw_fwd_kernel<<<64, 64, 0, stream>>>(skew, decg, dumpg);
  dtw_bt_kernel<<<64, 256, 69760, stream>>>(skew, decg, colsum, out);
}

// Round 14
// 280.437 us; speedup vs baseline: 1.4713x; 1.0185x over previous
//
#include <hip/hip_runtime.h>
#include <hip/hip_bf16.h>
#include <stdint.h>

typedef __attribute__((ext_vector_type(8))) short short8v;     // 8 x bf16 (MFMA A/B frag)
typedef __attribute__((ext_vector_type(4))) float float4v;     // MFMA C/D frag / vec loads
typedef __attribute__((ext_vector_type(4))) unsigned short ushort4v;
typedef __attribute__((ext_vector_type(4))) unsigned int uint4v;

#define FINF __builtin_huge_valf()
#define BB 64
#define NN 512
#define DD 256
#define TT_SKEW 768   // skew rows: tau = r + 4*(j>>3) in [0, 511+252] -> pad to 768

// ws layout (bytes):
//   [0,        16777216)  xnb bf16 [B][N][D]
//   [16777216, 33554432)  ynb bf16 [B][N][D]
//   [33554432, 83886080)  cost_skew bf16 [B][768][512] (cell (r,j) at row tau=r+4*(j>>3), col j)
//   [83886080, 84017152)  colsum f32 [B][512] (column sums of cost, from GEMM epilogue)

static __device__ __forceinline__ unsigned short f2bf(float f) {
  union { float f; uint32_t u; } a; a.f = f;
  uint32_t r = a.u + 0x7fffu + ((a.u >> 16) & 1u);   // RNE
  return (unsigned short)(r >> 16);
}
static __device__ __forceinline__ float bf2f(uint16_t v) {
  return __uint_as_float(((uint32_t)v) << 16);
}

// ---------------- Kernel 0: zero the colsum buffer ----------------
__global__ __launch_bounds__(256) void zero_colsum_kernel(float* __restrict__ colsum)
{
  colsum[blockIdx.x * 256 + threadIdx.x] = 0.0f;
}

// ---------------- Kernel 1: row-normalize + cast to bf16 ----------------
__global__ __launch_bounds__(256) void norm_cast_kernel(
    const float* __restrict__ x, const float* __restrict__ y,
    uint16_t* __restrict__ xnb, uint16_t* __restrict__ ynb)
{
  const int wave = threadIdx.x >> 6, lane = threadIdx.x & 63;
  const int row = blockIdx.x * 4 + wave;
  const float* src; uint16_t* dst;
  if (row < BB * NN) { src = x + (size_t)row * DD;            dst = xnb + (size_t)row * DD; }
  else               { src = y + (size_t)(row - BB*NN) * DD;  dst = ynb + (size_t)(row - BB*NN) * DD; }
  const float4v v = *(const float4v*)(src + lane * 4);
  float s = v[0]*v[0] + v[1]*v[1] + v[2]*v[2] + v[3]*v[3];
  #pragma unroll
  for (int d = 1; d < 64; d <<= 1) s += __shfl_xor(s, d, 64);
  const float inv = 1.0f / fmaxf(sqrtf(s), 1e-8f);
  ushort4v o;
  o[0] = f2bf(v[0] * inv); o[1] = f2bf(v[1] * inv);
  o[2] = f2bf(v[2] * inv); o[3] = f2bf(v[3] * inv);
  *(ushort4v*)(dst + lane * 4) = o;
}

// ---------------- Kernel 2: cost = 1 - xn·yn -> bf16 skew + colsum atomics ----------------
__global__ __launch_bounds__(256) void gemm_cost_kernel(
    const uint16_t* __restrict__ xnb, const uint16_t* __restrict__ ynb,
    uint16_t* __restrict__ skew, float* __restrict__ colsum)
{
  __shared__ uint16_t As[128 * 32];
  __shared__ uint16_t Bs[128 * 32];
  const int bid = blockIdx.x;
  const int b = bid >> 4, tm = (bid >> 2) & 3, tn = bid & 3;
  const int tid = threadIdx.x, wave = tid >> 6, lane = tid & 63;
  const int wr = wave >> 1, wc = wave & 1;

  const char* Ab = (const char*)(xnb + (size_t)b * NN * DD + (size_t)tm * 128 * DD);
  const char* Bb = (const char*)(ynb + (size_t)b * NN * DD + (size_t)tn * 128 * DD);

  float4v acc[4][4];
  #pragma unroll
  for (int i = 0; i < 4; i++)
    #pragma unroll
    for (int j = 0; j < 4; j++) acc[i][j] = (float4v){0.f, 0.f, 0.f, 0.f};

  const int seg0 = wave * 2;
  const int o0 = seg0 * 1024 + lane * 16;
  const int o1 = o0 + 1024;
  const int r0 = o0 >> 6, c0 = o0 & 63;
  const int r1 = o1 >> 6, c1 = o1 & 63;

  for (int kk = 0; kk < 8; kk++) {
    const int kb = kk * 64;
    __builtin_amdgcn_global_load_lds(
        (const __attribute__((address_space(1))) uint32_t*)(Ab + (size_t)r0 * 512 + kb + c0),
        (__attribute__((address_space(3))) uint32_t*)((char*)As + seg0 * 1024), 16, 0, 0);
    __builtin_amdgcn_global_load_lds(
        (const __attribute__((address_space(1))) uint32_t*)(Ab + (size_t)r1 * 512 + kb + c1),
        (__attribute__((address_space(3))) uint32_t*)((char*)As + (seg0 + 1) * 1024), 16, 0, 0);
    __builtin_amdgcn_global_load_lds(
        (const __attribute__((address_space(1))) uint32_t*)(Bb + (size_t)r0 * 512 + kb + c0),
        (__attribute__((address_space(3))) uint32_t*)((char*)Bs + seg0 * 1024), 16, 0, 0);
    __builtin_amdgcn_global_load_lds(
        (const __attribute__((address_space(1))) uint32_t*)(Bb + (size_t)r1 * 512 + kb + c1),
        (__attribute__((address_space(3))) uint32_t*)((char*)Bs + (seg0 + 1) * 1024), 16, 0, 0);
    __syncthreads();

    short8v af[4], bfr[4];
    #pragma unroll
    for (int mi = 0; mi < 4; mi++) {
      const int rr = wr * 64 + mi * 16 + (lane & 15);
      af[mi] = *(const short8v*)((const char*)As + rr * 64 + (lane >> 4) * 16);
    }
    #pragma unroll
    for (int nj = 0; nj < 4; nj++) {
      const int rr = wc * 64 + nj * 16 + (lane & 15);
      bfr[nj] = *(const short8v*)((const char*)Bs + rr * 64 + (lane >> 4) * 16);
    }
    #pragma unroll
    for (int mi = 0; mi < 4; mi++)
      #pragma unroll
      for (int nj = 0; nj < 4; nj++)
        acc[mi][nj] = __builtin_amdgcn_mfma_f32_16x16x32_bf16(af[mi], bfr[nj], acc[mi][nj], 0, 0, 0);
    __syncthreads();
  }

  uint16_t* Cb = skew + (size_t)b * TT_SKEW * NN;
  #pragma unroll
  for (int mi = 0; mi < 4; mi++)
    #pragma unroll
    for (int nj = 0; nj < 4; nj++) {
      const int cc = tn * 128 + wc * 64 + nj * 16 + (lane & 15);
      const int lg = cc >> 3;
      #pragma unroll
      for (int v = 0; v < 4; v++) {
        const int rr = tm * 128 + wr * 64 + mi * 16 + (lane >> 4) * 4 + v;
        Cb[(size_t)(rr + 4 * lg) * NN + cc] = f2bf(1.0f - acc[mi][nj][v]);
      }
    }

  // column-sum partials (for neg LSE): sum cost over this wave's 64 rows
  #pragma unroll
  for (int nj = 0; nj < 4; nj++) {
    const int cc = tn * 128 + wc * 64 + nj * 16 + (lane & 15);
    float s = 0.f;
    #pragma unroll
    for (int mi = 0; mi < 4; mi++)
      #pragma unroll
      for (int v = 0; v < 4; v++) s += 1.0f - acc[mi][nj][v];
    s += __shfl_xor(s, 16, 64);
    s += __shfl_xor(s, 32, 64);
    if (lane < 16) atomicAdd(&colsum[b * 512 + cc], s);
  }
}

// ---------------- Kernel 3: DTW forward + backtrack + LSEs (merged) ----------------
// 64 blocks x 1 wave. Forward identical to R13's 4-rows/lane/step loop, but
// decisions go to LDS (never global): 8 MB of dec traffic + the bt kernel's
// launch + 64KB copy are eliminated. With stores out of the loop, every step
// is exactly 4 loads -> UNIFORM vmcnt(12), no peel. After the loop the same
// wave does: neg LSE (from GEMM's colsum), lane-0 region-walk backtrack over
// LDS dec, per-lane colpos accumulation, pos LSE, out[b].
// LDS: dec u32 (a*512 + w*4, w<128) [0,64K) | dump [64K,64K+512) |
//      rlo 66048 | rhi 67072 | colpos 68096 | total 70144 B.
__global__ __launch_bounds__(64, 1) void dtw_fwdbt_kernel(
    const uint16_t* __restrict__ skew, const float* __restrict__ colsum,
    float* __restrict__ out)
{
  extern __shared__ char lds_raw[];
  const int l = threadIdx.x;
  const int b = blockIdx.x;
  const uint16_t* csk = skew + (size_t)b * TT_SKEW * NN;
  const uint64_t base64 = (uint64_t)(uintptr_t)csk + 16u * (uint32_t)l;
  const bool is0 = (l == 0);

  uint4v rg[4][4];                       // [slot][row-in-step]
  #pragma unroll
  for (int i = 0; i < 4; ++i)
    #pragma unroll
    for (int k = 0; k < 4; ++k) {
      const uint64_t a = base64 + ((uint64_t)(4 * i + k) << 10);
      asm volatile("global_load_dwordx4 %0, %1, off" : "=v"(rg[i][k]) : "v"(a));
    }

  float tp[8];
  #pragma unroll
  for (int c = 0; c < 8; ++c) tp[c] = FINF;
  float cl0 = FINF, cl1 = FINF, cl2 = FINF, cl3 = FINF, carry = FINF;

  auto UNPACK = [&](const uint4v R, float (&S)[8]) {
    const float a0 = __uint_as_float(R[0] << 16);
    const float a1 = __uint_as_float(R[0] & 0xFFFF0000u);
    const float a2 = __uint_as_float(R[1] << 16);
    const float a3 = __uint_as_float(R[1] & 0xFFFF0000u);
    const float a4 = __uint_as_float(R[2] << 16);
    const float a5 = __uint_as_float(R[2] & 0xFFFF0000u);
    const float a6 = __uint_as_float(R[3] << 16);
    const float a7 = __uint_as_float(R[3] & 0xFFFF0000u);
    S[0] = a0; S[1] = S[0] + a1; S[2] = S[1] + a2; S[3] = S[2] + a3;
    S[4] = S[3] + a4; S[5] = S[4] + a5; S[6] = S[5] + a6; S[7] = S[6] + a7;
  };

  // One DP row: up[] holds previous row's tc in, this row's tc out.
  auto ROW = [&](const float (&S)[8], float (&up)[8], float leftv, float diag0,
                 uint32_t &word, int sh) {
    float dcp[8], mu[8], w[8], PW[8], tn[8];
    dcp[0] = diag0;
    #pragma unroll
    for (int c = 1; c < 8; ++c) dcp[c] = up[c - 1];
    #pragma unroll
    for (int c = 0; c < 8; ++c) mu[c] = fminf(dcp[c], up[c]);
    w[0] = mu[0];
    #pragma unroll
    for (int c = 1; c < 8; ++c) w[c] = mu[c] - S[c - 1];
    PW[0] = w[0];
    #pragma unroll
    for (int c = 1; c < 8; ++c) PW[c] = fminf(PW[c - 1], w[c]);
    #pragma unroll
    for (int c = 0; c < 8; ++c) tn[c] = fminf(PW[c], leftv) + S[c];
    float lc[8];
    lc[0] = leftv;
    #pragma unroll
    for (int c = 1; c < 8; ++c) lc[c] = tn[c - 1];
    #pragma unroll
    for (int c = 0; c < 8; ++c) {
      // tie-break diag > up > left (== reference equality chain)
      const uint32_t e = (up[c] < dcp[c]) ? 1u : 0u;
      const uint32_t d = (lc[c] < mu[c]) ? 2u : e;
      word |= d << (sh + 2 * c);
    }
    #pragma unroll
    for (int c = 0; c < 8; ++c) up[c] = tn[c];
  };

  auto STEP = [&](int t, const uint4v R0, const uint4v R1,
                  const uint4v R2, const uint4v R3) {
    // 4 back-to-back shuffles -> one DS round
    const float s0r = __shfl_up(cl0, 1, 64);
    const float s1r = __shfl_up(cl1, 1, 64);
    const float s2r = __shfl_up(cl2, 1, 64);
    const float s3r = __shfl_up(cl3, 1, 64);
    float S0[8], S1[8], S2[8], S3[8];
    UNPACK(R0, S0); UNPACK(R1, S1); UNPACK(R2, S2); UNPACK(R3, S3);
    const float sh0 = is0 ? ((t == 0) ? 0.0f : FINF) : s0r;  // left, row0
    const float sh1 = is0 ? FINF : s1r;
    const float sh2 = is0 ? FINF : s2r;
    const float sh3 = is0 ? FINF : s3r;
    const float dgA = carry;                 // diag col0, row0 = prev step's sh3
    const float dg1 = is0 ? FINF : s0r;      // diag col0, row k = sh_{k-1}
    const float dg2 = is0 ? FINF : s1r;
    const float dg3 = is0 ? FINF : s2r;
    carry = sh3;

    const uint32_t a = (uint32_t)(t - l);
    const bool valid = a < 128u;

    float up[8];
    #pragma unroll
    for (int c = 0; c < 8; ++c) up[c] = tp[c];
    uint32_t w0 = 0, w1 = 0;
    ROW(S0, up, sh0, dgA, w0, 0);  const float h0 = up[7];
    ROW(S1, up, sh1, dg1, w0, 16); const float h1 = up[7];
    ROW(S2, up, sh2, dg2, w1, 0);  const float h2 = up[7];
    ROW(S3, up, sh3, dg3, w1, 16); const float h3 = up[7];

    // dec words to LDS (4B lane stride: 2-way, free). dump slot for invalid.
    const uint32_t byte0 = valid ? ((a << 9) | (((uint32_t)l) << 2))
                                 : (65536u | (((uint32_t)l) << 2));
    *(uint32_t*)(lds_raw + byte0) = w0;
    *(uint32_t*)(lds_raw + byte0 + 256) = w1;

    #pragma unroll
    for (int c = 0; c < 8; ++c) tp[c] = valid ? up[c] : tp[c];
    cl0 = valid ? h0 : cl0;
    cl1 = valid ? h1 : cl1;
    cl2 = valid ? h2 : cl2;
    cl3 = valid ? h3 : cl3;
  };

  auto RELOAD = [&](int u, int t) {   // rows 4(t+4)..+3, clamped in-bounds
    int rr = 4 * (t + 4); if (rr > 764) rr = 764;
    #pragma unroll
    for (int k = 0; k < 4; ++k) {
      const uint64_t a = base64 + ((uint64_t)(rr + k) << 10);
      asm volatile("global_load_dwordx4 %0, %1, off" : "=v"(rg[u][k]) : "v"(a));
    }
  };

  // uniform pipeline: 16 loads outstanding; each wait retires slot u's 4
  for (int t0 = 0; t0 < 192; t0 += 4) {
    #pragma unroll
    for (int u = 0; u < 4; ++u) {
      const int t = t0 + u;
      asm volatile("s_waitcnt vmcnt(12)"
                   : "+v"(rg[u][0]), "+v"(rg[u][1]), "+v"(rg[u][2]), "+v"(rg[u][3]));
      STEP(t, rg[u][0], rg[u][1], rg[u][2], rg[u][3]);
      RELOAD(u, t);
    }
  }
  asm volatile("s_waitcnt vmcnt(0)" ::: "memory");

  uint16_t* rlo    = (uint16_t*)(lds_raw + 66048);
  uint16_t* rhi    = (uint16_t*)(lds_raw + 67072);
  float*    colpos = (float*)  (lds_raw + 68096);
  const uint32_t* dec32 = (const uint32_t*)lds_raw;

  for (int r = l; r < NN; r += 64) { rlo[r] = 1; rhi[r] = 0; colpos[r] = 0.0f; }

  // ---- neg = LSE over colsum[b][0..511] (computed by GEMM epilogue) ----
  const float* cs = colsum + (size_t)b * 512;
  float nv[8];
  float m = -FINF;
  #pragma unroll
  for (int k = 0; k < 8; ++k) { nv[k] = cs[l + 64 * k]; m = fmaxf(m, nv[k]); }
  #pragma unroll
  for (int d = 1; d < 64; d <<= 1) m = fmaxf(m, __shfl_xor(m, d, 64));
  float e = 0.f;
  #pragma unroll
  for (int k = 0; k < 8; ++k) e += expf(nv[k] - m);
  #pragma unroll
  for (int d = 1; d < 64; d <<= 1) e += __shfl_xor(e, d, 64);
  const float neg = m + logf(e);
  __syncthreads();

  // ---- backtrack (lane 0): region-cached walk over LDS dec ----
  if (l == 0) {
    int i = NN - 1, j = NN - 1, hicur = NN - 1;
    while (i > 0 && j > 0) {
      const int a = i >> 2, g2 = j >> 3;
      const uint32_t w0 = dec32[a * 128 + g2];        // rows 4a,4a+1
      const uint32_t w1 = dec32[a * 128 + 64 + g2];   // rows 4a+2,4a+3
      const int ilo = a << 2, jlo = g2 << 3;
      while (i >= ilo && j >= jlo && i > 0 && j > 0) {
        const uint32_t w = (i & 2) ? w1 : w0;
        const uint32_t dd = (w >> (((i & 1) << 4) + ((j & 7) << 1))) & 3u;
        if (dd == 2u) { j--; }           // left: stay in row
        else {
          rlo[i] = (uint16_t)j; rhi[i] = (uint16_t)hicur;  // leave row i
          i--;
          if (dd == 0u) j--;             // diag also moves left
          hicur = j;                     // entry column of new row
        }
      }
    }
    rlo[i] = (uint16_t)j; rhi[i] = (uint16_t)hicur;      // pending row at exit
  }
  __syncthreads();

  // ---- colpos: 8 rows per lane (4-row skew addressing) ----
  for (int r = l; r < NN; r += 64) {
    const int lo = rlo[r], hi = rhi[r];
    for (int j = lo; j <= hi; j++) {
      const float cv = bf2f(csk[(size_t)(r + 4 * (j >> 3)) * NN + j]);
      atomicAdd(&colpos[j], cv);
    }
  }
  if (l == 0 && rlo[0] != 0) atomicAdd(&colpos[0], bf2f(csk[0]));
  __syncthreads();

  // ---- pos = LSE over colpos[512] ----
  float mv[8];
  float mx2 = -FINF;
  #pragma unroll
  for (int k = 0; k < 8; k++) { mv[k] = colpos[l + 64 * k]; mx2 = fmaxf(mx2, mv[k]); }
  #pragma unroll
  for (int d = 1; d < 64; d <<= 1) mx2 = fmaxf(mx2, __shfl_xor(mx2, d, 64));
  float se2 = 0.f;
  #pragma unroll
  for (int k = 0; k < 8; k++) se2 += expf(mv[k] - mx2);
  #pragma unroll
  for (int d = 1; d < 64; d <<= 1) se2 += __shfl_xor(se2, d, 64);
  const float pos = mx2 + logf(se2);

  if (l == 0) out[b] = pos - neg;
}

extern "C" void kernel_launch(void* const* d_in, const int* in_sizes, int n_in,
                              void* d_out, int out_size, void* d_ws, size_t ws_size,
                              hipStream_t stream)
{
  (void)in_sizes; (void)n_in; (void)out_size; (void)ws_size;
  const float* x = (const float*)d_in[0];
  const float* y = (const float*)d_in[1];
  float* out = (float*)d_out;
  char* ws = (char*)d_ws;
  uint16_t* xnb   = (uint16_t*)ws;
  uint16_t* ynb   = (uint16_t*)(ws + (size_t)16777216);
  uint16_t* skew  = (uint16_t*)(ws + (size_t)33554432);
  float*   colsum = (float*)   (ws + (size_t)83886080);

  (void)hipFuncSetAttribute((const void*)dtw_fwdbt_kernel,
                            hipFuncAttributeMaxDynamicSharedMemorySize, 70144);

  zero_colsum_kernel<<<128, 256, 0, stream>>>(colsum);
  norm_cast_kernel<<<16384, 256, 0, stream>>>(x, y, xnb, ynb);
  gemm_cost_kernel<<<1024, 256, 0, stream>>>(xnb, ynb, skew, colsum);
  dtw_fwdbt_kernel<<<64, 64, 70144, stream>>>(skew, colsum, out);
}

// Round 18
// 251.858 us; speedup vs baseline: 1.6383x; 1.1135x over previous
//
#include <hip/hip_runtime.h>
#include <hip/hip_bf16.h>
#include <stdint.h>

typedef __attribute__((ext_vector_type(8))) short short8v;     // 8 x bf16 (MFMA A/B frag)
typedef __attribute__((ext_vector_type(4))) float float4v;     // MFMA C/D frag / vec loads
typedef __attribute__((ext_vector_type(4))) unsigned short ushort4v;
typedef __attribute__((ext_vector_type(4))) unsigned int uint4v;

#define FINF __builtin_huge_valf()
#define BB 64
#define NN 512
#define DD 256
#define TT_SKEW 640   // skew rows: tau = r + 2*(j>>3) in [0, 511+126] -> pad to 640

// ws layout (bytes):
//   [0,        16777216)  xnb bf16 [B][N][D]
//   [16777216, 33554432)  ynb bf16 [B][N][D]
//   [33554432, 75497472)  cost_skew bf16 [B][640][512] (cell (r,j) at row tau=r+2*(j>>3), col j)
//   [75497472, 75628544)  colsum f32 [B][512]

static __device__ __forceinline__ unsigned short f2bf(float f) {
  union { float f; uint32_t u; } a; a.f = f;
  uint32_t r = a.u + 0x7fffu + ((a.u >> 16) & 1u);   // RNE
  return (unsigned short)(r >> 16);
}
static __device__ __forceinline__ float bf2f(uint16_t v) {
  return __uint_as_float(((uint32_t)v) << 16);
}

// ---------------- Kernel 0: zero the colsum buffer ----------------
__global__ __launch_bounds__(256) void zero_colsum_kernel(float* __restrict__ colsum)
{
  colsum[blockIdx.x * 256 + threadIdx.x] = 0.0f;
}

// ---------------- Kernel 1: row-normalize + cast to bf16 ----------------
__global__ __launch_bounds__(256) void norm_cast_kernel(
    const float* __restrict__ x, const float* __restrict__ y,
    uint16_t* __restrict__ xnb, uint16_t* __restrict__ ynb)
{
  const int wave = threadIdx.x >> 6, lane = threadIdx.x & 63;
  const int row = blockIdx.x * 4 + wave;
  const float* src; uint16_t* dst;
  if (row < BB * NN) { src = x + (size_t)row * DD;            dst = xnb + (size_t)row * DD; }
  else               { src = y + (size_t)(row - BB*NN) * DD;  dst = ynb + (size_t)(row - BB*NN) * DD; }
  const float4v v = *(const float4v*)(src + lane * 4);
  float s = v[0]*v[0] + v[1]*v[1] + v[2]*v[2] + v[3]*v[3];
  #pragma unroll
  for (int d = 1; d < 64; d <<= 1) s += __shfl_xor(s, d, 64);
  const float inv = 1.0f / fmaxf(sqrtf(s), 1e-8f);
  ushort4v o;
  o[0] = f2bf(v[0] * inv); o[1] = f2bf(v[1] * inv);
  o[2] = f2bf(v[2] * inv); o[3] = f2bf(v[3] * inv);
  *(ushort4v*)(dst + lane * 4) = o;
}

// ---------------- Kernel 2: cost = 1 - xn·yn -> bf16 skew + colsum atomics ----------------
// R8's proven 2-row-skew gemm + R13's proven colsum epilogue.
__global__ __launch_bounds__(256) void gemm_cost_kernel(
    const uint16_t* __restrict__ xnb, const uint16_t* __restrict__ ynb,
    uint16_t* __restrict__ skew, float* __restrict__ colsum)
{
  __shared__ uint16_t As[128 * 32];
  __shared__ uint16_t Bs[128 * 32];
  const int bid = blockIdx.x;
  const int b = bid >> 4, tm = (bid >> 2) & 3, tn = bid & 3;
  const int tid = threadIdx.x, wave = tid >> 6, lane = tid & 63;
  const int wr = wave >> 1, wc = wave & 1;

  const char* Ab = (const char*)(xnb + (size_t)b * NN * DD + (size_t)tm * 128 * DD);
  const char* Bb = (const char*)(ynb + (size_t)b * NN * DD + (size_t)tn * 128 * DD);

  float4v acc[4][4];
  #pragma unroll
  for (int i = 0; i < 4; i++)
    #pragma unroll
    for (int j = 0; j < 4; j++) acc[i][j] = (float4v){0.f, 0.f, 0.f, 0.f};

  const int seg0 = wave * 2;
  const int o0 = seg0 * 1024 + lane * 16;
  const int o1 = o0 + 1024;
  const int r0 = o0 >> 6, c0 = o0 & 63;
  const int r1 = o1 >> 6, c1 = o1 & 63;

  for (int kk = 0; kk < 8; kk++) {
    const int kb = kk * 64;
    __builtin_amdgcn_global_load_lds(
        (const __attribute__((address_space(1))) uint32_t*)(Ab + (size_t)r0 * 512 + kb + c0),
        (__attribute__((address_space(3))) uint32_t*)((char*)As + seg0 * 1024), 16, 0, 0);
    __builtin_amdgcn_global_load_lds(
        (const __attribute__((address_space(1))) uint32_t*)(Ab + (size_t)r1 * 512 + kb + c1),
        (__attribute__((address_space(3))) uint32_t*)((char*)As + (seg0 + 1) * 1024), 16, 0, 0);
    __builtin_amdgcn_global_load_lds(
        (const __attribute__((address_space(1))) uint32_t*)(Bb + (size_t)r0 * 512 + kb + c0),
        (__attribute__((address_space(3))) uint32_t*)((char*)Bs + seg0 * 1024), 16, 0, 0);
    __builtin_amdgcn_global_load_lds(
        (const __attribute__((address_space(1))) uint32_t*)(Bb + (size_t)r1 * 512 + kb + c1),
        (__attribute__((address_space(3))) uint32_t*)((char*)Bs + (seg0 + 1) * 1024), 16, 0, 0);
    __syncthreads();

    short8v af[4], bfr[4];
    #pragma unroll
    for (int mi = 0; mi < 4; mi++) {
      const int rr = wr * 64 + mi * 16 + (lane & 15);
      af[mi] = *(const short8v*)((const char*)As + rr * 64 + (lane >> 4) * 16);
    }
    #pragma unroll
    for (int nj = 0; nj < 4; nj++) {
      const int rr = wc * 64 + nj * 16 + (lane & 15);
      bfr[nj] = *(const short8v*)((const char*)Bs + rr * 64 + (lane >> 4) * 16);
    }
    #pragma unroll
    for (int mi = 0; mi < 4; mi++)
      #pragma unroll
      for (int nj = 0; nj < 4; nj++)
        acc[mi][nj] = __builtin_amdgcn_mfma_f32_16x16x32_bf16(af[mi], bfr[nj], acc[mi][nj], 0, 0, 0);
    __syncthreads();
  }

  uint16_t* Cb = skew + (size_t)b * TT_SKEW * NN;
  #pragma unroll
  for (int mi = 0; mi < 4; mi++)
    #pragma unroll
    for (int nj = 0; nj < 4; nj++) {
      const int cc = tn * 128 + wc * 64 + nj * 16 + (lane & 15);
      const int lg = cc >> 3;
      #pragma unroll
      for (int v = 0; v < 4; v++) {
        const int rr = tm * 128 + wr * 64 + mi * 16 + (lane >> 4) * 4 + v;
        Cb[(size_t)(rr + 2 * lg) * NN + cc] = f2bf(1.0f - acc[mi][nj][v]);
      }
    }

  // column-sum partials (for neg LSE)
  #pragma unroll
  for (int nj = 0; nj < 4; nj++) {
    const int cc = tn * 128 + wc * 64 + nj * 16 + (lane & 15);
    float s = 0.f;
    #pragma unroll
    for (int mi = 0; mi < 4; mi++)
      #pragma unroll
      for (int v = 0; v < 4; v++) s += 1.0f - acc[mi][nj][v];
    s += __shfl_xor(s, 16, 64);
    s += __shfl_xor(s, 32, 64);
    if (lane < 16) atomicAdd(&colsum[b * 512 + cc], s);
  }
}

// ---------------- Kernel 3: DTW forward (R8 verbatim) + in-wave backtrack ----------------
// 64 blocks x 1 wave. Forward loop is R8's PASSED kernel unchanged: 8-slot x
// 2-row register ring (SGPR-saddr asm loads), uniform vmcnt(14) (loads only),
// prefix-scan STEP with MASKED state updates (garbage from unwritten skew pad
// cells is discarded by the valid mask -> deterministic, R13-proven without
// pad_zero), dec words to LDS (dump slot for invalid). Then, instead of
// dumping dec to global, the same wave runs the epilogue (R14-proven merge):
// neg LSE from GEMM's colsum, lane-0 backtrack with R8's exact walk over LDS
// dec, colpos accumulation, pos LSE, out[b].
// LDS: dec u32[256][64] 64KB | dump [65536,65792) | rlo 65792 | rhi 66816 |
//      colpos 67840 | total 69888 B.
__global__ __launch_bounds__(64, 1) void dtw_fwdbt_kernel(
    const uint16_t* __restrict__ skew, const float* __restrict__ colsum,
    float* __restrict__ out)
{
  extern __shared__ char lds_raw[];
  const int l = threadIdx.x;
  const int b = blockIdx.x;
  const uint16_t* csk = skew + (size_t)b * TT_SKEW * NN;
  const uint64_t base = (uint64_t)(uintptr_t)csk;
  const bool is0 = (l == 0);
  const uint32_t voff_base = 16u * (uint32_t)l;
  const uint32_t dump_addr = 65536u + (((uint32_t)l) << 2);

  uint4v ringA[8], ringB[8];     // rows 2t (A) and 2t+1 (B)
  #pragma unroll
  for (int i = 0; i < 8; ++i) {
    const uint32_t voA = voff_base + ((uint32_t)(2 * i) << 10);
    const uint32_t voB = voA + 1024u;
    asm volatile("global_load_dwordx4 %0, %1, %2" : "=v"(ringA[i]) : "v"(voA), "s"(base));
    asm volatile("global_load_dwordx4 %0, %1, %2" : "=v"(ringB[i]) : "v"(voB), "s"(base));
  }

  float tp[8];
  #pragma unroll
  for (int c = 0; c < 8; ++c) tp[c] = FINF;
  float cl0 = FINF, cl1 = FINF, carry = FINF;

  for (int t0 = 0; t0 < 320; t0 += 8) {
    #pragma unroll
    for (int u = 0; u < 8; ++u) {
      const int t = t0 + u;
      float shA = __shfl_up(cl0, 1, 64);   // tc[r0][8l-1]
      float shB = __shfl_up(cl1, 1, 64);   // tc[r1][8l-1]
      if (is0) { shA = (t == 0) ? 0.0f : FINF; shB = FINF; }
      const float sh_p0 = carry;            // tc[r0-1][8l-1]
      carry = shB;
      const float shA1 = is0 ? FINF : shA;  // row1 diag col0 (INF at l=0)

      asm volatile("s_waitcnt vmcnt(14)" : "+v"(ringA[u]), "+v"(ringB[u]));
      const uint4v A = ringA[u];
      const uint4v Bv = ringB[u];

      const uint32_t rlane = (uint32_t)(t - l);
      const bool valid = rlane < 256u;

      // unpack both rows + prefix sums
      float ca[8], cbv[8], S0[8], S1[8];
      #pragma unroll
      for (int k = 0; k < 4; ++k) {
        ca[2*k]   = __uint_as_float(A[k] << 16);
        ca[2*k+1] = __uint_as_float(A[k] & 0xFFFF0000u);
        cbv[2*k]   = __uint_as_float(Bv[k] << 16);
        cbv[2*k+1] = __uint_as_float(Bv[k] & 0xFFFF0000u);
      }
      S0[0] = ca[0]; S1[0] = cbv[0];
      #pragma unroll
      for (int c = 1; c < 8; ++c) { S0[c] = S0[c-1] + ca[c]; S1[c] = S1[c-1] + cbv[c]; }

      // ---- row 0 ----
      float dcp0[8], mu0[8], w0[8], PW0[8], tn0[8];
      dcp0[0] = sh_p0;
      #pragma unroll
      for (int c = 1; c < 8; ++c) dcp0[c] = tp[c-1];
      #pragma unroll
      for (int c = 0; c < 8; ++c) mu0[c] = fminf(dcp0[c], tp[c]);
      w0[0] = mu0[0];
      #pragma unroll
      for (int c = 1; c < 8; ++c) w0[c] = mu0[c] - S0[c-1];
      PW0[0] = w0[0];
      #pragma unroll
      for (int c = 1; c < 8; ++c) PW0[c] = fminf(PW0[c-1], w0[c]);
      #pragma unroll
      for (int c = 0; c < 8; ++c) tn0[c] = fminf(PW0[c], shA) + S0[c];

      // ---- row 1 (chains on row 0 in-lane) ----
      float dcp1[8], mu1[8], w1[8], PW1[8], tn1[8];
      dcp1[0] = shA1;
      #pragma unroll
      for (int c = 1; c < 8; ++c) dcp1[c] = tn0[c-1];
      #pragma unroll
      for (int c = 0; c < 8; ++c) mu1[c] = fminf(dcp1[c], tn0[c]);
      w1[0] = mu1[0];
      #pragma unroll
      for (int c = 1; c < 8; ++c) w1[c] = mu1[c] - S1[c-1];
      PW1[0] = w1[0];
      #pragma unroll
      for (int c = 1; c < 8; ++c) PW1[c] = fminf(PW1[c-1], w1[c]);
      #pragma unroll
      for (int c = 0; c < 8; ++c) tn1[c] = fminf(PW1[c], shB) + S1[c];

      // ---- decisions (ref tie-break diag > up > left): dd=(lc<mu)?2:(up<dcp) ----
      uint32_t word = 0;
      {
        float lc0[8], lc1[8];
        lc0[0] = shA; lc1[0] = shB;
        #pragma unroll
        for (int c = 1; c < 8; ++c) { lc0[c] = tn0[c-1]; lc1[c] = tn1[c-1]; }
        #pragma unroll
        for (int c = 0; c < 8; ++c) {
          const uint32_t e0 = (tp[c] < dcp0[c]) ? 1u : 0u;
          const uint32_t d0 = (lc0[c] < mu0[c]) ? 2u : e0;
          const uint32_t e1 = (tn0[c] < dcp1[c]) ? 1u : 0u;
          const uint32_t d1 = (lc1[c] < mu1[c]) ? 2u : e1;
          word |= (d0 << (2 * c)) | (d1 << (16 + 2 * c));
        }
      }
      const uint32_t waddr = valid ? ((rlane << 8) + (((uint32_t)l) << 2)) : dump_addr;
      *(uint32_t*)(lds_raw + waddr) = word;

      #pragma unroll
      for (int c = 0; c < 8; ++c) tp[c] = valid ? tn1[c] : tp[c];
      cl0 = valid ? tn0[7] : cl0;
      cl1 = tp[7];

      // refill rows 2(t+8), 2(t+8)+1 (clamped; keeps exactly 16 in flight)
      {
        int rr = 2 * (t + 8); if (rr > 638) rr = 638;
        const uint32_t voA = voff_base + ((uint32_t)rr << 10);
        const uint32_t voB = voA + 1024u;
        asm volatile("global_load_dwordx4 %0, %1, %2" : "=v"(ringA[u]) : "v"(voA), "s"(base));
        asm volatile("global_load_dwordx4 %0, %1, %2" : "=v"(ringB[u]) : "v"(voB), "s"(base));
      }
    }
  }
  asm volatile("s_waitcnt vmcnt(0)" ::: "memory");
  __syncthreads();

  // ---------------- in-wave epilogue (R14-proven merge pattern) ----------------
  uint16_t* rlo    = (uint16_t*)(lds_raw + 65792);
  uint16_t* rhi    = (uint16_t*)(lds_raw + 66816);
  float*    colpos = (float*)  (lds_raw + 67840);
  const uint32_t* dec32 = (const uint32_t*)lds_raw;

  for (int r = l; r < NN; r += 64) { rlo[r] = 1; rhi[r] = 0; colpos[r] = 0.0f; }

  // ---- neg = LSE over colsum[b][0..511] (computed by GEMM epilogue) ----
  const float* cs = colsum + (size_t)b * 512;
  float nv[8];
  float m = -FINF;
  #pragma unroll
  for (int k = 0; k < 8; ++k) { nv[k] = cs[l + 64 * k]; m = fmaxf(m, nv[k]); }
  #pragma unroll
  for (int d = 1; d < 64; d <<= 1) m = fmaxf(m, __shfl_xor(m, d, 64));
  float e = 0.f;
  #pragma unroll
  for (int k = 0; k < 8; ++k) e += expf(nv[k] - m);
  #pragma unroll
  for (int d = 1; d < 64; d <<= 1) e += __shfl_xor(e, d, 64);
  const float neg = m + logf(e);
  __syncthreads();

  // ---- backtrack (lane 0): R8's exact walk over the LDS dec array ----
  if (l == 0) {
    int i = NN - 1, j = NN - 1, hicur = NN - 1;
    int cidx = -1; uint32_t cw = 0;
    while (i > 0 && j > 0) {
      const int widx = (i >> 1) * 64 + (j >> 3);
      if (widx != cidx) { cw = dec32[widx]; cidx = widx; }
      const uint32_t dd = (cw >> (((i & 1) << 4) + ((j & 7) << 1))) & 3u;
      if (dd == 2u) { j--; }           // left: stay in row
      else {
        rlo[i] = (uint16_t)j; rhi[i] = (uint16_t)hicur;  // leave row i
        i--;
        if (dd == 0u) j--;             // diag also moves left
        hicur = j;                     // entry column of new row
      }
    }
    rlo[i] = (uint16_t)j; rhi[i] = (uint16_t)hicur;      // pending row at exit
  }
  __syncthreads();

  // ---- colpos: 8 rows per lane (2-row skew addressing) ----
  for (int r = l; r < NN; r += 64) {
    const int lo = rlo[r], hi = rhi[r];
    for (int j = lo; j <= hi; j++) {
      const float cv = bf2f(csk[(size_t)(r + 2 * (j >> 3)) * NN + j]);
      atomicAdd(&colpos[j], cv);
    }
  }
  if (l == 0 && rlo[0] != 0) atomicAdd(&colpos[0], bf2f(csk[0]));
  __syncthreads();

  // ---- pos = LSE over colpos[512] ----
  float mv[8];
  float mx2 = -FINF;
  #pragma unroll
  for (int k = 0; k < 8; k++) { mv[k] = colpos[l + 64 * k]; mx2 = fmaxf(mx2, mv[k]); }
  #pragma unroll
  for (int d = 1; d < 64; d <<= 1) mx2 = fmaxf(mx2, __shfl_xor(mx2, d, 64));
  float se2 = 0.f;
  #pragma unroll
  for (int k = 0; k < 8; k++) se2 += expf(mv[k] - mx2);
  #pragma unroll
  for (int d = 1; d < 64; d <<= 1) se2 += __shfl_xor(se2, d, 64);
  const float pos = mx2 + logf(se2);

  if (l == 0) out[b] = pos - neg;
}

extern "C" void kernel_launch(void* const* d_in, const int* in_sizes, int n_in,
                              void* d_out, int out_size, void* d_ws, size_t ws_size,
                              hipStream_t stream)
{
  (void)in_sizes; (void)n_in; (void)out_size; (void)ws_size;
  const float* x = (const float*)d_in[0];
  const float* y = (const float*)d_in[1];
  float* out = (float*)d_out;
  char* ws = (char*)d_ws;
  uint16_t* xnb   = (uint16_t*)ws;
  uint16_t* ynb   = (uint16_t*)(ws + (size_t)16777216);
  uint16_t* skew  = (uint16_t*)(ws + (size_t)33554432);
  float*   colsum = (float*)   (ws + (size_t)75497472);

  (void)hipFuncSetAttribute((const void*)dtw_fwdbt_kernel,
                            hipFuncAttributeMaxDynamicSharedMemorySize, 69888);

  zero_colsum_kernel<<<128, 256, 0, stream>>>(colsum);
  norm_cast_kernel<<<16384, 256, 0, stream>>>(x, y, xnb, ynb);
  gemm_cost_kernel<<<1024, 256, 0, stream>>>(xnb, ynb, skew, colsum);
  dtw_fwdbt_kernel<<<64, 64, 69888, stream>>>(skew, colsum, out);
}